// Round 7
// baseline (740.811 us; speedup 1.0000x reference)
//
#include <hip/hip_runtime.h>
#include <hip/hip_bf16.h>

typedef unsigned short u16;
typedef unsigned int   u32;
typedef _Float16 f16;
typedef __attribute__((ext_vector_type(8))) _Float16 f16x8;
typedef __attribute__((ext_vector_type(4))) _Float16 f16x4;
typedef __attribute__((ext_vector_type(4))) float    f32x4;
typedef __attribute__((ext_vector_type(8))) unsigned short u16x8;

#define BATCH 4
#define CH 512
#define NN 4096
#define CQ 64

__device__ __forceinline__ float bf2f(u16 v) {
    union { unsigned int u; float f; } x; x.u = ((unsigned int)v) << 16; return x.f;
}

// ---------------------------------------------------------------------------
// Input dtype detector (safety net): 0 = fp32 inputs, 1 = bf16 inputs.
// ---------------------------------------------------------------------------
__global__ __launch_bounds__(64) void detect_kernel(const u32* __restrict__ xw,
                                                    int* __restrict__ flag)
{
    const u32 w  = xw[threadIdx.x];
    const u32 ex = (w >> 23) & 0xFFu;
    const int plausible = (ex >= 100u && ex <= 132u) ? 1 : 0;
    const unsigned long long m = __ballot(plausible);
    if (threadIdx.x == 0) flag[0] = (__popcll(m) >= 48) ? 0 : 1;
}

// ---------------------------------------------------------------------------
// Projection GEMM (fp32 VALU, verified): outputs f16.
//   o <  64 : -> fT[b][n][o]      (f16, [N][CQ])
//   o < 128 : -> gT[b][n][o-64]   (f16, [N][CQ])
//   else    : -> hv[b][o-128][n]  (f16, [CH][N])
// ---------------------------------------------------------------------------
__global__ __launch_bounds__(256) void proj_kernel(
    const void* __restrict__ xin, const void* __restrict__ Wq,
    const void* __restrict__ Wk, const void* __restrict__ Wv,
    const int* __restrict__ flag,
    f16* __restrict__ fT, f16* __restrict__ gT, f16* __restrict__ hv)
{
    const int isbf = *flag;
    const int nb = blockIdx.x;
    const int rb = blockIdx.y;
    const int b  = blockIdx.z;
    const int n0 = nb * 64, o0 = rb * 64;
    const int t  = threadIdx.x;
    const int ty = t >> 4, tx = t & 15;

    __shared__ float Wl[64][68];
    __shared__ float Xl[64][68];

    float acc[4][4];
#pragma unroll
    for (int r = 0; r < 4; ++r)
#pragma unroll
        for (int q = 0; q < 4; ++q) acc[r][q] = 0.f;

    const int so = t >> 2;
    const int sk = (t & 3) * 16;

    const void* wsrc; int wrow;
    {
        const int go = o0 + so;
        if (go < 64)       { wsrc = Wq; wrow = go; }
        else if (go < 128) { wsrc = Wk; wrow = go - 64; }
        else               { wsrc = Wv; wrow = go - 128; }
    }

    for (int k0 = 0; k0 < CH; k0 += 64) {
        if (isbf) {
            {
                const u16* p = (const u16*)wsrc + (size_t)wrow * CH + k0 + sk;
                const u16x8 w0 = *(const u16x8*)p;
                const u16x8 w1 = *(const u16x8*)(p + 8);
#pragma unroll
                for (int e = 0; e < 8; ++e) Wl[sk + e][so] = bf2f(w0[e]);
#pragma unroll
                for (int e = 0; e < 8; ++e) Wl[sk + 8 + e][so] = bf2f(w1[e]);
            }
            {
                const u16* p = (const u16*)xin +
                               ((size_t)(b * CH + k0 + so)) * NN + n0 + sk;
                const u16x8 x0 = *(const u16x8*)p;
                const u16x8 x1 = *(const u16x8*)(p + 8);
                *(float4*)&Xl[so][sk] =
                    make_float4(bf2f(x0[0]), bf2f(x0[1]), bf2f(x0[2]), bf2f(x0[3]));
                *(float4*)&Xl[so][sk + 4] =
                    make_float4(bf2f(x0[4]), bf2f(x0[5]), bf2f(x0[6]), bf2f(x0[7]));
                *(float4*)&Xl[so][sk + 8] =
                    make_float4(bf2f(x1[0]), bf2f(x1[1]), bf2f(x1[2]), bf2f(x1[3]));
                *(float4*)&Xl[so][sk + 12] =
                    make_float4(bf2f(x1[4]), bf2f(x1[5]), bf2f(x1[6]), bf2f(x1[7]));
            }
        } else {
            {
                const float* p = (const float*)wsrc + (size_t)wrow * CH + k0 + sk;
                const float4 a0 = ((const float4*)p)[0];
                const float4 a1 = ((const float4*)p)[1];
                const float4 a2 = ((const float4*)p)[2];
                const float4 a3 = ((const float4*)p)[3];
                const float av[16] = {a0.x,a0.y,a0.z,a0.w, a1.x,a1.y,a1.z,a1.w,
                                      a2.x,a2.y,a2.z,a2.w, a3.x,a3.y,a3.z,a3.w};
#pragma unroll
                for (int e = 0; e < 16; ++e) Wl[sk + e][so] = av[e];
            }
            {
                const float* p = (const float*)xin +
                                 ((size_t)(b * CH + k0 + so)) * NN + n0 + sk;
                *(float4*)&Xl[so][sk]      = ((const float4*)p)[0];
                *(float4*)&Xl[so][sk + 4]  = ((const float4*)p)[1];
                *(float4*)&Xl[so][sk + 8]  = ((const float4*)p)[2];
                *(float4*)&Xl[so][sk + 12] = ((const float4*)p)[3];
            }
        }
        __syncthreads();
#pragma unroll 16
        for (int kk = 0; kk < 64; ++kk) {
            const float4 a  = *(const float4*)&Wl[kk][ty * 4];
            const float4 bv = *(const float4*)&Xl[kk][tx * 4];
            const float av[4] = {a.x, a.y, a.z, a.w};
            const float bb[4] = {bv.x, bv.y, bv.z, bv.w};
#pragma unroll
            for (int r = 0; r < 4; ++r)
#pragma unroll
                for (int q = 0; q < 4; ++q) acc[r][q] += av[r] * bb[q];
        }
        __syncthreads();
    }

#pragma unroll
    for (int r = 0; r < 4; ++r) {
        const int o = o0 + ty * 4 + r;
#pragma unroll
        for (int q = 0; q < 4; ++q) {
            const int n = n0 + tx * 4 + q;
            if (o < CQ) {
                fT[((size_t)b * NN + n) * CQ + o] = (f16)acc[r][q];
            } else if (o < 2 * CQ) {
                gT[((size_t)b * NN + n) * CQ + (o - CQ)] = (f16)acc[r][q];
            } else {
                hv[((size_t)b * CH + (o - 2 * CQ)) * NN + n] = (f16)acc[r][q];
            }
        }
    }
}

// ---------------------------------------------------------------------------
// K1: ST[bz][j][i] = (f16) sum_k g[k,j] f[k,i]   (scores transposed: row j)
//     lsum[b][j]  += sum_i exp(f32(f16(S)))      (fused, in-wave reduce+atomic)
// No max subtraction: sigma(S)~8, max|S|~50 -> exp fits fp32 comfortably.
// One-shot K=64 (no K-loop). Block 512 thr = 8 waves (4 j x 2 i), tile 128x128.
// ---------------------------------------------------------------------------
__global__ __launch_bounds__(512) void score_kernel(
    const f16* __restrict__ fT, const f16* __restrict__ gT,
    f16* __restrict__ ST, float* __restrict__ lsum, int b0)
{
    const int ibk = blockIdx.x;          // i-block 0..31
    const int jbk = blockIdx.y;          // j-block 0..31
    const int bz  = blockIdx.z;          // chunk-local batch
    const int b   = b0 + bz;
    const int t   = threadIdx.x;
    const int w   = t >> 6, l = t & 63;
    const int c16 = l & 15, h = l >> 4;
    const int wr  = w >> 1;              // j quarter 0..3
    const int wc  = w & 1;               // i half 0..1
    const int j0  = jbk * 128 + wr * 32;
    const int i0  = ibk * 128 + wc * 64;

    const f16* fb_ = fT + (size_t)b * NN * CQ;
    const f16* gb_ = gT + (size_t)b * NN * CQ;

    f16x8 ga[2][2], fbr[4][2];
#pragma unroll
    for (int ja = 0; ja < 2; ++ja)
#pragma unroll
        for (int kc = 0; kc < 2; ++kc)
            ga[ja][kc] = *(const f16x8*)(gb_ +
                (size_t)(j0 + 16 * ja + c16) * CQ + 32 * kc + 8 * h);
#pragma unroll
    for (int ii = 0; ii < 4; ++ii)
#pragma unroll
        for (int kc = 0; kc < 2; ++kc)
            fbr[ii][kc] = *(const f16x8*)(fb_ +
                (size_t)(i0 + 16 * ii + c16) * CQ + 32 * kc + 8 * h);

    f32x4 s[2][4];
#pragma unroll
    for (int ja = 0; ja < 2; ++ja)
#pragma unroll
        for (int ii = 0; ii < 4; ++ii)
#pragma unroll
            for (int r = 0; r < 4; ++r) s[ja][ii][r] = 0.f;

#pragma unroll
    for (int ja = 0; ja < 2; ++ja)
#pragma unroll
        for (int ii = 0; ii < 4; ++ii) {
            s[ja][ii] = __builtin_amdgcn_mfma_f32_16x16x32_f16(
                            ga[ja][0], fbr[ii][0], s[ja][ii], 0, 0, 0);
            s[ja][ii] = __builtin_amdgcn_mfma_f32_16x16x32_f16(
                            ga[ja][1], fbr[ii][1], s[ja][ii], 0, 0, 0);
        }

    // epilogue: store f16 S^T + fused exp-sum over i
    f16* Sb = ST + (size_t)bz * NN * NN;
    float rsum[2][4];
#pragma unroll
    for (int ja = 0; ja < 2; ++ja)
#pragma unroll
        for (int r = 0; r < 4; ++r) rsum[ja][r] = 0.f;

#pragma unroll
    for (int ja = 0; ja < 2; ++ja)
#pragma unroll
        for (int ii = 0; ii < 4; ++ii)
#pragma unroll
            for (int r = 0; r < 4; ++r) {
                const f16 hx = (f16)s[ja][ii][r];
                Sb[(size_t)(j0 + 16 * ja + 4 * h + r) * NN + i0 + 16 * ii + c16] = hx;
                rsum[ja][r] += __expf((float)hx);
            }

#pragma unroll
    for (int ja = 0; ja < 2; ++ja)
#pragma unroll
        for (int r = 0; r < 4; ++r) {
            float v = rsum[ja][r];
            v += __shfl_xor(v, 1);
            v += __shfl_xor(v, 2);
            v += __shfl_xor(v, 4);
            v += __shfl_xor(v, 8);
            if (c16 == 0)
                atomicAdd(&lsum[(size_t)b * NN + j0 + 16 * ja + 4 * h + r], v);
        }
}

// ---------------------------------------------------------------------------
// K3: out[b][c][j] = gamma * sum_i hv[c,i] * exp(ST[j,i]) / l[j]  +  x[b][c][j]
// Plain MFMA GEMM, B-operand transformed in registers (exp * 1/l), f16.
// ZERO barriers, zero LDS: 16 independent waves/block (4 c-slices x 4 j-tiles).
// Block = 1024 thr, covers 512 c x 64 j. XCD-swizzled so each batch's 4MB hv
// stays in its XCDs' L2 while ST streams from HBM.
// ---------------------------------------------------------------------------
__global__ __launch_bounds__(1024) void pv_kernel(
    const void* __restrict__ xin, const f16* __restrict__ hv,
    const f16* __restrict__ ST, const float* __restrict__ lsum,
    const void* __restrict__ gammap, const int* __restrict__ flag,
    float* __restrict__ out, int b0, int bc)
{
    const int isbf = *flag;
    const int bid  = blockIdx.x;          // 0 .. 64*bc-1
    const int xcd  = bid & 7;
    const int s_   = bid >> 3;            // 0 .. 8*bc-1
    const int perb = 8 / bc;              // XCDs per batch
    const int bz   = xcd / perb;
    const int b    = b0 + bz;
    const int jblk = (xcd % perb) * (8 * bc) + s_;   // 0..63
    const int j0   = jblk * 64;

    const int t   = threadIdx.x;
    const int w   = t >> 6, l = t & 63;
    const int c16 = l & 15, h = l >> 4;
    const int wr  = w >> 2;               // c slice 0..3 (128 each)
    const int wj  = w & 3;                // j tile 0..3 (16 each)
    const int jw  = j0 + wj * 16 + c16;   // this lane's output column j

    const float rl = 1.0f / lsum[(size_t)b * NN + jw];
    const f16* hb = hv + (size_t)b * CH * NN + (size_t)(wr * 128 + c16) * NN;
    const f16* Sr = ST + (size_t)(xcd / perb) * NN * NN + (size_t)jw * NN;

    f32x4 oacc[8];
#pragma unroll
    for (int ct = 0; ct < 8; ++ct)
#pragma unroll
        for (int r = 0; r < 4; ++r) oacc[ct][r] = 0.f;

    for (int i0 = 0; i0 < NN; i0 += 32) {
        const f16x8 sv = *(const f16x8*)(Sr + i0 + 8 * h);
        f16x8 pb;
#pragma unroll
        for (int e = 0; e < 8; ++e)
            pb[e] = (f16)(__expf((float)sv[e]) * rl);
#pragma unroll
        for (int ct = 0; ct < 8; ++ct) {
            const f16x8 a = *(const f16x8*)(hb + (size_t)(16 * ct) * NN + i0 + 8 * h);
            oacc[ct] = __builtin_amdgcn_mfma_f32_16x16x32_f16(a, pb, oacc[ct], 0, 0, 0);
        }
    }

    float gam;
    if (isbf) gam = bf2f(((const u16*)gammap)[0]);
    else      gam = ((const float*)gammap)[0];

#pragma unroll
    for (int ct = 0; ct < 8; ++ct)
#pragma unroll
        for (int r = 0; r < 4; ++r) {
            const int c = wr * 128 + 16 * ct + 4 * h + r;
            const size_t idx = ((size_t)b * CH + c) * NN + jw;
            float xv;
            if (isbf) xv = bf2f(((const u16*)xin)[idx]);
            else      xv = ((const float*)xin)[idx];
            out[idx] = gam * oacc[ct][r] + xv;
        }
}

// ---------------------------------------------------------------------------
// Fallback flash kernel (round 6, passed @296us) for small ws_size.
// ---------------------------------------------------------------------------
__global__ __launch_bounds__(512, 2) void attn_mfma(
    const void* __restrict__ xin, const f16* __restrict__ fT,
    const f16* __restrict__ gT, const f16* __restrict__ hv,
    const void* __restrict__ gammap, const int* __restrict__ flag,
    float* __restrict__ out)
{
    const int isbf = *flag;
    const int bid  = blockIdx.x;
    const int xcd  = bid & 7, slot = bid >> 3;
    const int b    = xcd >> 1;
    const int jblk = ((xcd & 1) << 6) + slot;
    const int j0   = jblk * 32;
    const int t    = threadIdx.x;
    const int w    = t >> 6;
    const int l    = t & 63;
    const int j16  = l & 15;
    const int h    = l >> 4;

    __shared__ f16   Pp[32 * 256];
    __shared__ float wmax[8][2][16];
    __shared__ float wsum[8][2][16];

    f16x8 gf[2][2];
#pragma unroll
    for (int jb = 0; jb < 2; ++jb)
#pragma unroll
        for (int kc = 0; kc < 2; ++kc)
            gf[jb][kc] = *(const f16x8*)(gT +
                ((size_t)b * NN + j0 + 16 * jb + j16) * CQ + 32 * kc + 8 * h);

    f32x4 oacc[4][2];
#pragma unroll
    for (int cb = 0; cb < 4; ++cb)
#pragma unroll
        for (int jb = 0; jb < 2; ++jb)
#pragma unroll
            for (int r = 0; r < 4; ++r) oacc[cb][jb][r] = 0.f;

    float m_run[2] = {-1e30f, -1e30f};
    float l_run[2] = {0.f, 0.f};

    const f16* fbase = fT + (size_t)b * NN * CQ;
    const f16* hbase = hv + (size_t)b * CH * NN;

    f16x8 fa[2][2];
    {
        const int irow0 = 32 * w + j16;
        fa[0][0] = *(const f16x8*)(fbase + (size_t)irow0 * CQ + 8 * h);
        fa[0][1] = *(const f16x8*)(fbase + (size_t)irow0 * CQ + 32 + 8 * h);
        fa[1][0] = *(const f16x8*)(fbase + (size_t)(irow0 + 16) * CQ + 8 * h);
        fa[1][1] = *(const f16x8*)(fbase + (size_t)(irow0 + 16) * CQ + 32 + 8 * h);
    }
    f16x8 aA[4], aB[4];

#define LDA(BUF, KC, I0BASE)                                                  \
    {                                                                         \
        _Pragma("unroll")                                                     \
        for (int cb = 0; cb < 4; ++cb)                                        \
            BUF[cb] = *(const f16x8*)(hbase +                                 \
                (size_t)(64 * w + 16 * cb + j16) * NN +                       \
                (I0BASE) + 32 * (KC) + 8 * h);                                \
    }

#define PVST(BUF, KC)                                                         \
    {                                                                         \
        const int sw0 = (4 * (KC) + h) ^ j16;                                 \
        const f16x8 pf0 = *(const f16x8*)&Pp[j16 * 256 + sw0 * 8];            \
        const f16x8 pf1 = *(const f16x8*)&Pp[(16 + j16) * 256 + sw0 * 8];     \
        _Pragma("unroll")                                                     \
        for (int cb = 0; cb < 4; ++cb) {                                      \
            oacc[cb][0] = __builtin_amdgcn_mfma_f32_16x16x32_f16(             \
                              BUF[cb], pf0, oacc[cb][0], 0, 0, 0);            \
            oacc[cb][1] = __builtin_amdgcn_mfma_f32_16x16x32_f16(             \
                              BUF[cb], pf1, oacc[cb][1], 0, 0, 0);            \
        }                                                                     \
    }

    LDA(aA, 0, 0);
    LDA(aB, 1, 0);

    for (int it = 0; it < 16; ++it) {
        const int i0 = it * 256;

        f32x4 s[2][2];
#pragma unroll
        for (int ib = 0; ib < 2; ++ib)
#pragma unroll
            for (int jb = 0; jb < 2; ++jb)
#pragma unroll
                for (int r = 0; r < 4; ++r) s[ib][jb][r] = 0.f;

#pragma unroll
        for (int ib = 0; ib < 2; ++ib)
#pragma unroll
            for (int jb = 0; jb < 2; ++jb) {
                s[ib][jb] = __builtin_amdgcn_mfma_f32_16x16x32_f16(
                                fa[ib][0], gf[jb][0], s[ib][jb], 0, 0, 0);
                s[ib][jb] = __builtin_amdgcn_mfma_f32_16x16x32_f16(
                                fa[ib][1], gf[jb][1], s[ib][jb], 0, 0, 0);
            }

        float pmax[2];
#pragma unroll
        for (int jb = 0; jb < 2; ++jb) {
            float m0 = fmaxf(fmaxf(s[0][jb][0], s[0][jb][1]),
                             fmaxf(s[0][jb][2], s[0][jb][3]));
            float m1 = fmaxf(fmaxf(s[1][jb][0], s[1][jb][1]),
                             fmaxf(s[1][jb][2], s[1][jb][3]));
            float mm = fmaxf(m0, m1);
            mm = fmaxf(mm, __shfl_xor(mm, 16));
            mm = fmaxf(mm, __shfl_xor(mm, 32));
            pmax[jb] = mm;
        }
        if (h == 0) { wmax[w][0][j16] = pmax[0]; wmax[w][1][j16] = pmax[1]; }
        __syncthreads();

        float m_new[2], sc[2];
#pragma unroll
        for (int jb = 0; jb < 2; ++jb) {
            float tm = wmax[0][jb][j16];
#pragma unroll
            for (int w2 = 1; w2 < 8; ++w2) tm = fmaxf(tm, wmax[w2][jb][j16]);
            m_new[jb] = fmaxf(m_run[jb], tm);
            sc[jb]    = __expf(m_run[jb] - m_new[jb]);
            m_run[jb] = m_new[jb];
        }

        float psum[2] = {0.f, 0.f};
#pragma unroll
        for (int ib = 0; ib < 2; ++ib) {
#pragma unroll
            for (int jb = 0; jb < 2; ++jb) {
                const float p0 = __expf(s[ib][jb][0] - m_new[jb]);
                const float p1 = __expf(s[ib][jb][1] - m_new[jb]);
                const float p2 = __expf(s[ib][jb][2] - m_new[jb]);
                const float p3 = __expf(s[ib][jb][3] - m_new[jb]);
                psum[jb] += (p0 + p1) + (p2 + p3);
                f16x4 v4;
                v4[0] = (f16)p0; v4[1] = (f16)p1; v4[2] = (f16)p2; v4[3] = (f16)p3;
                const int jloc = 16 * jb + j16;
                const int sw   = (4 * w + 2 * ib + (h >> 1)) ^ j16;
                *(f16x4*)&Pp[jloc * 256 + sw * 8 + (h & 1) * 4] = v4;
            }
        }
#pragma unroll
        for (int jb = 0; jb < 2; ++jb) {
            psum[jb] += __shfl_xor(psum[jb], 16);
            psum[jb] += __shfl_xor(psum[jb], 32);
        }
        if (h == 0) { wsum[w][0][j16] = psum[0]; wsum[w][1][j16] = psum[1]; }

#pragma unroll
        for (int cb = 0; cb < 4; ++cb)
#pragma unroll
            for (int jb = 0; jb < 2; ++jb)
#pragma unroll
                for (int r = 0; r < 4; ++r) oacc[cb][jb][r] *= sc[jb];

        __syncthreads();

#pragma unroll
        for (int jb = 0; jb < 2; ++jb) {
            float ts = 0.f;
#pragma unroll
            for (int w2 = 0; w2 < 8; ++w2) ts += wsum[w2][jb][j16];
            l_run[jb] = l_run[jb] * sc[jb] + ts;
        }

        const int i0n = (it < 15) ? (i0 + 256) : 0;
        {
            const int irow0 = i0n + 32 * w + j16;
            fa[0][0] = *(const f16x8*)(fbase + (size_t)irow0 * CQ + 8 * h);
            fa[0][1] = *(const f16x8*)(fbase + (size_t)irow0 * CQ + 32 + 8 * h);
            fa[1][0] = *(const f16x8*)(fbase + (size_t)(irow0 + 16) * CQ + 8 * h);
            fa[1][1] = *(const f16x8*)(fbase + (size_t)(irow0 + 16) * CQ + 32 + 8 * h);
        }
        PVST(aA, 0); LDA(aA, 2, i0);
        PVST(aB, 1); LDA(aB, 3, i0);
        PVST(aA, 2); LDA(aA, 4, i0);
        PVST(aB, 3); LDA(aB, 5, i0);
        PVST(aA, 4); LDA(aA, 6, i0);
        PVST(aB, 5); LDA(aB, 7, i0);
        PVST(aA, 6); LDA(aA, 0, i0n);
        PVST(aB, 7); LDA(aB, 1, i0n);
    }

    float gam;
    if (isbf) gam = bf2f(((const u16*)gammap)[0]);
    else      gam = ((const float*)gammap)[0];

    const float inv0 = gam / l_run[0];
    const float inv1 = gam / l_run[1];

#pragma unroll
    for (int cb = 0; cb < 4; ++cb) {
#pragma unroll
        for (int jb = 0; jb < 2; ++jb) {
            const float invj = jb ? inv1 : inv0;
            const int j = j0 + 16 * jb + j16;
#pragma unroll
            for (int r = 0; r < 4; ++r) {
                const int c = 64 * w + 16 * cb + 4 * h + r;
                const size_t idx = ((size_t)b * CH + c) * NN + j;
                float xv;
                if (isbf) xv = bf2f(((const u16*)xin)[idx]);
                else      xv = ((const float*)xin)[idx];
                out[idx] = oacc[cb][jb][r] * invj + xv;
            }
        }
    }
#undef LDA
#undef PVST
}

extern "C" void kernel_launch(void* const* d_in, const int* in_sizes, int n_in,
                              void* d_out, int out_size, void* d_ws, size_t ws_size,
                              hipStream_t stream)
{
    // ws layout:
    //  [flag 256B][lsum f32 64KB][fT f16 2MB][gT f16 2MB][hv f16 16MB][ST f16 ...]
    const size_t off_l  = 256;
    const size_t off_fT = off_l  + (size_t)BATCH * NN * 4;
    const size_t off_gT = off_fT + (size_t)BATCH * NN * CQ * 2;
    const size_t off_hv = off_gT + (size_t)BATCH * NN * CQ * 2;
    const size_t off_ST = off_hv + (size_t)BATCH * CH * NN * 2;
    const size_t stN    = (size_t)NN * NN * 2;   // 33.55 MB per batch

    int*   flag = (int*)d_ws;
    float* lsum = (float*)((char*)d_ws + off_l);
    f16*   fT   = (f16*)((char*)d_ws + off_fT);
    f16*   gT   = (f16*)((char*)d_ws + off_gT);
    f16*   hv   = (f16*)((char*)d_ws + off_hv);
    f16*   ST   = (f16*)((char*)d_ws + off_ST);

    int bc = 0;
    if      (ws_size >= off_ST + 4 * stN) bc = 4;
    else if (ws_size >= off_ST + 2 * stN) bc = 2;
    else if (ws_size >= off_ST + 1 * stN) bc = 1;

    detect_kernel<<<1, 64, 0, stream>>>((const u32*)d_in[0], flag);

    dim3 pgrid(64, 10, BATCH);
    proj_kernel<<<pgrid, 256, 0, stream>>>(d_in[0], d_in[1], d_in[2], d_in[3],
                                           flag, fT, gT, hv);

    if (bc) {
        hipMemsetAsync(lsum, 0, (size_t)BATCH * NN * 4, stream);
        for (int b0 = 0; b0 < BATCH; b0 += bc) {
            dim3 g1(32, 32, bc);
            score_kernel<<<g1, 512, 0, stream>>>(fT, gT, ST, lsum, b0);
            pv_kernel<<<64 * bc, 1024, 0, stream>>>(d_in[0], hv, ST, lsum,
                                                    d_in[4], flag,
                                                    (float*)d_out, b0, bc);
        }
    } else {
        attn_mfma<<<512, 512, 0, stream>>>(d_in[0], fT, gT, hv, d_in[4],
                                           flag, (float*)d_out);
    }
}

// Round 8
// 402.327 us; speedup vs baseline: 1.8413x; 1.8413x over previous
//
#include <hip/hip_runtime.h>
#include <hip/hip_bf16.h>

typedef unsigned short u16;
typedef unsigned int   u32;
typedef _Float16 f16;
typedef __attribute__((ext_vector_type(8))) _Float16 f16x8;
typedef __attribute__((ext_vector_type(4))) _Float16 f16x4;
typedef __attribute__((ext_vector_type(4))) float    f32x4;
typedef __attribute__((ext_vector_type(8))) unsigned short u16x8;

#define BATCH 4
#define CH 512
#define NN 4096
#define CQ 64
#define LOG2E 1.44269504f

__device__ __forceinline__ float bf2f(u16 v) {
    union { unsigned int u; float f; } x; x.u = ((unsigned int)v) << 16; return x.f;
}

// tiled ST layout: element (j,i) -> (j>>4)*65536 + (i>>3)*128 + (j&15)*8 + (i&7)
// pv B-frag (jt, i0, lane(j16,h)) = 16B at jt*65536 + ((i0>>3)+h)*128 + j16*8
__device__ __forceinline__ size_t stt_idx(int j, int i) {
    return (size_t)(j >> 4) * 65536 + (size_t)((i >> 3) * 128 + (j & 15) * 8 + (i & 7));
}

// ---------------------------------------------------------------------------
// Input dtype detector (safety net): 0 = fp32 inputs, 1 = bf16 inputs.
// ---------------------------------------------------------------------------
__global__ __launch_bounds__(64) void detect_kernel(const u32* __restrict__ xw,
                                                    int* __restrict__ flag)
{
    const u32 w  = xw[threadIdx.x];
    const u32 ex = (w >> 23) & 0xFFu;
    const int plausible = (ex >= 100u && ex <= 132u) ? 1 : 0;
    const unsigned long long m = __ballot(plausible);
    if (threadIdx.x == 0) flag[0] = (__popcll(m) >= 48) ? 0 : 1;
}

// ---------------------------------------------------------------------------
// Projection GEMM (fp32 VALU, verified): outputs f16.
// ---------------------------------------------------------------------------
__global__ __launch_bounds__(256) void proj_kernel(
    const void* __restrict__ xin, const void* __restrict__ Wq,
    const void* __restrict__ Wk, const void* __restrict__ Wv,
    const int* __restrict__ flag,
    f16* __restrict__ fT, f16* __restrict__ gT, f16* __restrict__ hv)
{
    const int isbf = *flag;
    const int nb = blockIdx.x;
    const int rb = blockIdx.y;
    const int b  = blockIdx.z;
    const int n0 = nb * 64, o0 = rb * 64;
    const int t  = threadIdx.x;
    const int ty = t >> 4, tx = t & 15;

    __shared__ float Wl[64][68];
    __shared__ float Xl[64][68];

    float acc[4][4];
#pragma unroll
    for (int r = 0; r < 4; ++r)
#pragma unroll
        for (int q = 0; q < 4; ++q) acc[r][q] = 0.f;

    const int so = t >> 2;
    const int sk = (t & 3) * 16;

    const void* wsrc; int wrow;
    {
        const int go = o0 + so;
        if (go < 64)       { wsrc = Wq; wrow = go; }
        else if (go < 128) { wsrc = Wk; wrow = go - 64; }
        else               { wsrc = Wv; wrow = go - 128; }
    }

    for (int k0 = 0; k0 < CH; k0 += 64) {
        if (isbf) {
            {
                const u16* p = (const u16*)wsrc + (size_t)wrow * CH + k0 + sk;
                const u16x8 w0 = *(const u16x8*)p;
                const u16x8 w1 = *(const u16x8*)(p + 8);
#pragma unroll
                for (int e = 0; e < 8; ++e) Wl[sk + e][so] = bf2f(w0[e]);
#pragma unroll
                for (int e = 0; e < 8; ++e) Wl[sk + 8 + e][so] = bf2f(w1[e]);
            }
            {
                const u16* p = (const u16*)xin +
                               ((size_t)(b * CH + k0 + so)) * NN + n0 + sk;
                const u16x8 x0 = *(const u16x8*)p;
                const u16x8 x1 = *(const u16x8*)(p + 8);
                *(float4*)&Xl[so][sk] =
                    make_float4(bf2f(x0[0]), bf2f(x0[1]), bf2f(x0[2]), bf2f(x0[3]));
                *(float4*)&Xl[so][sk + 4] =
                    make_float4(bf2f(x0[4]), bf2f(x0[5]), bf2f(x0[6]), bf2f(x0[7]));
                *(float4*)&Xl[so][sk + 8] =
                    make_float4(bf2f(x1[0]), bf2f(x1[1]), bf2f(x1[2]), bf2f(x1[3]));
                *(float4*)&Xl[so][sk + 12] =
                    make_float4(bf2f(x1[4]), bf2f(x1[5]), bf2f(x1[6]), bf2f(x1[7]));
            }
        } else {
            {
                const float* p = (const float*)wsrc + (size_t)wrow * CH + k0 + sk;
                const float4 a0 = ((const float4*)p)[0];
                const float4 a1 = ((const float4*)p)[1];
                const float4 a2 = ((const float4*)p)[2];
                const float4 a3 = ((const float4*)p)[3];
                const float av[16] = {a0.x,a0.y,a0.z,a0.w, a1.x,a1.y,a1.z,a1.w,
                                      a2.x,a2.y,a2.z,a2.w, a3.x,a3.y,a3.z,a3.w};
#pragma unroll
                for (int e = 0; e < 16; ++e) Wl[sk + e][so] = av[e];
            }
            {
                const float* p = (const float*)xin +
                                 ((size_t)(b * CH + k0 + so)) * NN + n0 + sk;
                *(float4*)&Xl[so][sk]      = ((const float4*)p)[0];
                *(float4*)&Xl[so][sk + 4]  = ((const float4*)p)[1];
                *(float4*)&Xl[so][sk + 8]  = ((const float4*)p)[2];
                *(float4*)&Xl[so][sk + 12] = ((const float4*)p)[3];
            }
        }
        __syncthreads();
#pragma unroll 16
        for (int kk = 0; kk < 64; ++kk) {
            const float4 a  = *(const float4*)&Wl[kk][ty * 4];
            const float4 bv = *(const float4*)&Xl[kk][tx * 4];
            const float av[4] = {a.x, a.y, a.z, a.w};
            const float bb[4] = {bv.x, bv.y, bv.z, bv.w};
#pragma unroll
            for (int r = 0; r < 4; ++r)
#pragma unroll
                for (int q = 0; q < 4; ++q) acc[r][q] += av[r] * bb[q];
        }
        __syncthreads();
    }

#pragma unroll
    for (int r = 0; r < 4; ++r) {
        const int o = o0 + ty * 4 + r;
#pragma unroll
        for (int q = 0; q < 4; ++q) {
            const int n = n0 + tx * 4 + q;
            if (o < CQ) {
                fT[((size_t)b * NN + n) * CQ + o] = (f16)acc[r][q];
            } else if (o < 2 * CQ) {
                gT[((size_t)b * NN + n) * CQ + (o - CQ)] = (f16)acc[r][q];
            } else {
                hv[((size_t)b * CH + (o - 2 * CQ)) * NN + n] = (f16)acc[r][q];
            }
        }
    }
}

// ---------------------------------------------------------------------------
// K1: ST (tiled layout) = f16(S^T * log2e); lsum[b][j] += sum_i exp2(f16 val)
// ---------------------------------------------------------------------------
__global__ __launch_bounds__(512) void score_kernel(
    const f16* __restrict__ fT, const f16* __restrict__ gT,
    f16* __restrict__ ST, float* __restrict__ lsum, int b0)
{
    const int ibk = blockIdx.x;
    const int jbk = blockIdx.y;
    const int bz  = blockIdx.z;
    const int b   = b0 + bz;
    const int t   = threadIdx.x;
    const int w   = t >> 6, l = t & 63;
    const int c16 = l & 15, h = l >> 4;
    const int wr  = w >> 1;
    const int wc  = w & 1;
    const int j0  = jbk * 128 + wr * 32;
    const int i0  = ibk * 128 + wc * 64;

    const f16* fb_ = fT + (size_t)b * NN * CQ;
    const f16* gb_ = gT + (size_t)b * NN * CQ;

    f16x8 ga[2][2], fbr[4][2];
#pragma unroll
    for (int ja = 0; ja < 2; ++ja)
#pragma unroll
        for (int kc = 0; kc < 2; ++kc)
            ga[ja][kc] = *(const f16x8*)(gb_ +
                (size_t)(j0 + 16 * ja + c16) * CQ + 32 * kc + 8 * h);
#pragma unroll
    for (int ii = 0; ii < 4; ++ii)
#pragma unroll
        for (int kc = 0; kc < 2; ++kc)
            fbr[ii][kc] = *(const f16x8*)(fb_ +
                (size_t)(i0 + 16 * ii + c16) * CQ + 32 * kc + 8 * h);

    f32x4 s[2][4];
#pragma unroll
    for (int ja = 0; ja < 2; ++ja)
#pragma unroll
        for (int ii = 0; ii < 4; ++ii)
#pragma unroll
            for (int r = 0; r < 4; ++r) s[ja][ii][r] = 0.f;

#pragma unroll
    for (int ja = 0; ja < 2; ++ja)
#pragma unroll
        for (int ii = 0; ii < 4; ++ii) {
            s[ja][ii] = __builtin_amdgcn_mfma_f32_16x16x32_f16(
                            ga[ja][0], fbr[ii][0], s[ja][ii], 0, 0, 0);
            s[ja][ii] = __builtin_amdgcn_mfma_f32_16x16x32_f16(
                            ga[ja][1], fbr[ii][1], s[ja][ii], 0, 0, 0);
        }

    f16* Sb = ST + (size_t)bz * NN * NN;
    float rsum[2][4];
#pragma unroll
    for (int ja = 0; ja < 2; ++ja)
#pragma unroll
        for (int r = 0; r < 4; ++r) rsum[ja][r] = 0.f;

#pragma unroll
    for (int ja = 0; ja < 2; ++ja)
#pragma unroll
        for (int ii = 0; ii < 4; ++ii)
#pragma unroll
            for (int r = 0; r < 4; ++r) {
                const f16 hx = (f16)(s[ja][ii][r] * LOG2E);
                const int jj = j0 + 16 * ja + 4 * h + r;
                const int ig = i0 + 16 * ii + c16;
                Sb[stt_idx(jj, ig)] = hx;
                rsum[ja][r] += exp2f((float)hx);
            }

#pragma unroll
    for (int ja = 0; ja < 2; ++ja)
#pragma unroll
        for (int r = 0; r < 4; ++r) {
            float v = rsum[ja][r];
            v += __shfl_xor(v, 1);
            v += __shfl_xor(v, 2);
            v += __shfl_xor(v, 4);
            v += __shfl_xor(v, 8);
            if (c16 == 0)
                atomicAdd(&lsum[(size_t)b * NN + j0 + 16 * ja + 4 * h + r], v);
        }
}

// ---------------------------------------------------------------------------
// K3: O = hv * exp2(ST)/l  as an LDS-staged GEMM (256c x 64j block, i-step 64).
// 8 waves = 2 cw x 4 jw; wave = 8 ct x 1 jt = 16 MFMA per i-step.
// A (hv) double-buffered in LDS in fragment order (conflict-free b128 both
// sides); B (ST tiled) 4-deep register ring from HBM; exp2 in regs.
// Raw s_barrier + lgkmcnt(0) only (no vmcnt drain of prefetch).
// ---------------------------------------------------------------------------
__global__ __launch_bounds__(512, 2) void pv_kernel(
    const void* __restrict__ xin, const f16* __restrict__ hv,
    const f16* __restrict__ ST, const float* __restrict__ lsum,
    const void* __restrict__ gammap, const int* __restrict__ flag,
    float* __restrict__ out, int b0, int bc)
{
    const int isbf = *flag;
    const int bid  = blockIdx.x;            // 0..128*bc-1
    const int xcd  = bid & 7;
    const int slot = bid >> 3;              // 0..16*bc-1
    const int perb = 8 / bc;
    const int bz   = xcd / perb;
    const int b    = b0 + bz;
    const int idx128 = (xcd % perb) * (16 * bc) + slot;  // 0..127
    const int jgrp = idx128 >> 1;           // 0..63
    const int cgrp = idx128 & 1;            // adjacent blocks share jgrp -> L2 hit
    const int c0b  = cgrp * 256;

    const int t = threadIdx.x;
    const int w = t >> 6, l = t & 63;
    const int j16 = l & 15, h = l >> 4;
    const int cw = w >> 2, jw = w & 3;
    const int jt   = jgrp * 4 + jw;
    const int jcol = jt * 16 + j16;
    const int c0w  = c0b + cw * 128;

    __shared__ f16 As[2][2][16][64][8];     // 64 KB: [buf][chunk][ct][lane][e]

    const f16*  hb = hv + (size_t)b * CH * NN;
    const f16*  Sb = ST + (size_t)bz * NN * NN + (size_t)jt * 65536 + j16 * 8;
    const float rl = 1.0f / lsum[(size_t)b * NN + jcol];

    f32x4 acc[8];
#pragma unroll
    for (int ct = 0; ct < 8; ++ct)
#pragma unroll
        for (int r = 0; r < 4; ++r) acc[ct][r] = 0.f;

    f16x8 areg[4];        // staging regs: q = ctl*2 + chunk
    f16x8 bring[4][2];    // B ring, depth 4

#define LD_A(I0)                                                              \
    {                                                                         \
        _Pragma("unroll")                                                     \
        for (int q = 0; q < 4; ++q) {                                         \
            const int ctl = q >> 1, ck = q & 1;                               \
            areg[q] = *(const f16x8*)(hb +                                    \
                (size_t)(c0b + (2 * w + ctl) * 16 + j16) * NN +               \
                (I0) + 32 * ck + 8 * h);                                      \
        }                                                                     \
    }

#define ST_A(BUF)                                                             \
    {                                                                         \
        _Pragma("unroll")                                                     \
        for (int q = 0; q < 4; ++q) {                                         \
            const int ctl = q >> 1, ck = q & 1;                               \
            *(f16x8*)&As[BUF][ck][2 * w + ctl][l][0] = areg[q];               \
        }                                                                     \
    }

#define LD_B(U, K)                                                            \
    {                                                                         \
        const int i0b = (K) * 64;                                             \
        bring[U][0] = *(const f16x8*)(Sb + ((i0b >> 3) + h) * 128);           \
        bring[U][1] = *(const f16x8*)(Sb + (((i0b + 32) >> 3) + h) * 128);    \
    }

    // ---- prologue ----
    LD_A(0);
    LD_B(0, 0); LD_B(1, 1); LD_B(2, 2); LD_B(3, 3);
    ST_A(0);                      // waits A(0) via reg deps
    LD_A(64);                     // A for iter 1, lands during iter 0
    asm volatile("s_waitcnt lgkmcnt(0)" ::: "memory");
    __builtin_amdgcn_s_barrier();

    for (int k4 = 0; k4 < 16; ++k4) {
#pragma unroll
        for (int u = 0; u < 4; ++u) {
            const int k   = k4 * 4 + u;
            const int cur = k & 1;

            // stage A(k+1) into buf[cur^1]; issue A(k+2)
            if (k < 63) ST_A(cur ^ 1);
            if (k < 62) { const int i0p = (k + 2) * 64; LD_A(i0p); }

            // B: consume ring slot u, reissue for k+4 (clamped)
            const f16x8 bv0 = bring[u][0];
            const f16x8 bv1 = bring[u][1];
            { const int kk = (k + 4 <= 63) ? (k + 4) : 63; LD_B(u, kk); }

            f16x8 pb0, pb1;
#pragma unroll
            for (int e = 0; e < 8; ++e) {
                pb0[e] = (f16)(exp2f((float)bv0[e]) * rl);
                pb1[e] = (f16)(exp2f((float)bv1[e]) * rl);
            }

            __builtin_amdgcn_s_setprio(1);
#pragma unroll
            for (int ct = 0; ct < 8; ++ct) {
                const f16x8 a0 = *(const f16x8*)&As[cur][0][cw * 8 + ct][l][0];
                acc[ct] = __builtin_amdgcn_mfma_f32_16x16x32_f16(a0, pb0, acc[ct], 0, 0, 0);
            }
#pragma unroll
            for (int ct = 0; ct < 8; ++ct) {
                const f16x8 a1 = *(const f16x8*)&As[cur][1][cw * 8 + ct][l][0];
                acc[ct] = __builtin_amdgcn_mfma_f32_16x16x32_f16(a1, pb1, acc[ct], 0, 0, 0);
            }
            __builtin_amdgcn_s_setprio(0);

            asm volatile("s_waitcnt lgkmcnt(0)" ::: "memory");
            __builtin_amdgcn_s_barrier();
        }
    }

    // ---- epilogue: out = gamma * acc + x ----
    float gam;
    if (isbf) gam = bf2f(((const u16*)gammap)[0]);
    else      gam = ((const float*)gammap)[0];

#pragma unroll
    for (int ct = 0; ct < 8; ++ct)
#pragma unroll
        for (int r = 0; r < 4; ++r) {
            const int c = c0w + ct * 16 + 4 * h + r;
            const size_t idx = ((size_t)b * CH + c) * NN + jcol;
            float xv;
            if (isbf) xv = bf2f(((const u16*)xin)[idx]);
            else      xv = ((const float*)xin)[idx];
            out[idx] = gam * acc[ct][r] + xv;
        }
#undef LD_A
#undef ST_A
#undef LD_B
}

// ---------------------------------------------------------------------------
// Fallback flash kernel (round 6, passed) for small ws_size.
// ---------------------------------------------------------------------------
__global__ __launch_bounds__(512, 2) void attn_mfma(
    const void* __restrict__ xin, const f16* __restrict__ fT,
    const f16* __restrict__ gT, const f16* __restrict__ hv,
    const void* __restrict__ gammap, const int* __restrict__ flag,
    float* __restrict__ out)
{
    const int isbf = *flag;
    const int bid  = blockIdx.x;
    const int xcd  = bid & 7, slot = bid >> 3;
    const int b    = xcd >> 1;
    const int jblk = ((xcd & 1) << 6) + slot;
    const int j0   = jblk * 32;
    const int t    = threadIdx.x;
    const int w    = t >> 6;
    const int l    = t & 63;
    const int j16  = l & 15;
    const int h    = l >> 4;

    __shared__ f16   Pp[32 * 256];
    __shared__ float wmax[8][2][16];
    __shared__ float wsum[8][2][16];

    f16x8 gf[2][2];
#pragma unroll
    for (int jb = 0; jb < 2; ++jb)
#pragma unroll
        for (int kc = 0; kc < 2; ++kc)
            gf[jb][kc] = *(const f16x8*)(gT +
                ((size_t)b * NN + j0 + 16 * jb + j16) * CQ + 32 * kc + 8 * h);

    f32x4 oacc[4][2];
#pragma unroll
    for (int cb = 0; cb < 4; ++cb)
#pragma unroll
        for (int jb = 0; jb < 2; ++jb)
#pragma unroll
            for (int r = 0; r < 4; ++r) oacc[cb][jb][r] = 0.f;

    float m_run[2] = {-1e30f, -1e30f};
    float l_run[2] = {0.f, 0.f};

    const f16* fbase = fT + (size_t)b * NN * CQ;
    const f16* hbase = hv + (size_t)b * CH * NN;

    f16x8 fa[2][2];
    {
        const int irow0 = 32 * w + j16;
        fa[0][0] = *(const f16x8*)(fbase + (size_t)irow0 * CQ + 8 * h);
        fa[0][1] = *(const f16x8*)(fbase + (size_t)irow0 * CQ + 32 + 8 * h);
        fa[1][0] = *(const f16x8*)(fbase + (size_t)(irow0 + 16) * CQ + 8 * h);
        fa[1][1] = *(const f16x8*)(fbase + (size_t)(irow0 + 16) * CQ + 32 + 8 * h);
    }
    f16x8 aA[4], aB[4];

#define LDA(BUF, KC, I0BASE)                                                  \
    {                                                                         \
        _Pragma("unroll")                                                     \
        for (int cb = 0; cb < 4; ++cb)                                        \
            BUF[cb] = *(const f16x8*)(hbase +                                 \
                (size_t)(64 * w + 16 * cb + j16) * NN +                       \
                (I0BASE) + 32 * (KC) + 8 * h);                                \
    }

#define PVST(BUF, KC)                                                         \
    {                                                                         \
        const int sw0 = (4 * (KC) + h) ^ j16;                                 \
        const f16x8 pf0 = *(const f16x8*)&Pp[j16 * 256 + sw0 * 8];            \
        const f16x8 pf1 = *(const f16x8*)&Pp[(16 + j16) * 256 + sw0 * 8];     \
        _Pragma("unroll")                                                     \
        for (int cb = 0; cb < 4; ++cb) {                                      \
            oacc[cb][0] = __builtin_amdgcn_mfma_f32_16x16x32_f16(             \
                              BUF[cb], pf0, oacc[cb][0], 0, 0, 0);            \
            oacc[cb][1] = __builtin_amdgcn_mfma_f32_16x16x32_f16(             \
                              BUF[cb], pf1, oacc[cb][1], 0, 0, 0);            \
        }                                                                     \
    }

    LDA(aA, 0, 0);
    LDA(aB, 1, 0);

    for (int it = 0; it < 16; ++it) {
        const int i0 = it * 256;

        f32x4 s[2][2];
#pragma unroll
        for (int ib = 0; ib < 2; ++ib)
#pragma unroll
            for (int jb = 0; jb < 2; ++jb)
#pragma unroll
                for (int r = 0; r < 4; ++r) s[ib][jb][r] = 0.f;

#pragma unroll
        for (int ib = 0; ib < 2; ++ib)
#pragma unroll
            for (int jb = 0; jb < 2; ++jb) {
                s[ib][jb] = __builtin_amdgcn_mfma_f32_16x16x32_f16(
                                fa[ib][0], gf[jb][0], s[ib][jb], 0, 0, 0);
                s[ib][jb] = __builtin_amdgcn_mfma_f32_16x16x32_f16(
                                fa[ib][1], gf[jb][1], s[ib][jb], 0, 0, 0);
            }

        float pmax[2];
#pragma unroll
        for (int jb = 0; jb < 2; ++jb) {
            float m0 = fmaxf(fmaxf(s[0][jb][0], s[0][jb][1]),
                             fmaxf(s[0][jb][2], s[0][jb][3]));
            float m1 = fmaxf(fmaxf(s[1][jb][0], s[1][jb][1]),
                             fmaxf(s[1][jb][2], s[1][jb][3]));
            float mm = fmaxf(m0, m1);
            mm = fmaxf(mm, __shfl_xor(mm, 16));
            mm = fmaxf(mm, __shfl_xor(mm, 32));
            pmax[jb] = mm;
        }
        if (h == 0) { wmax[w][0][j16] = pmax[0]; wmax[w][1][j16] = pmax[1]; }
        __syncthreads();

        float m_new[2], sc[2];
#pragma unroll
        for (int jb = 0; jb < 2; ++jb) {
            float tm = wmax[0][jb][j16];
#pragma unroll
            for (int w2 = 1; w2 < 8; ++w2) tm = fmaxf(tm, wmax[w2][jb][j16]);
            m_new[jb] = fmaxf(m_run[jb], tm);
            sc[jb]    = __expf(m_run[jb] - m_new[jb]);
            m_run[jb] = m_new[jb];
        }

        float psum[2] = {0.f, 0.f};
#pragma unroll
        for (int ib = 0; ib < 2; ++ib) {
#pragma unroll
            for (int jb = 0; jb < 2; ++jb) {
                const float p0 = __expf(s[ib][jb][0] - m_new[jb]);
                const float p1 = __expf(s[ib][jb][1] - m_new[jb]);
                const float p2 = __expf(s[ib][jb][2] - m_new[jb]);
                const float p3 = __expf(s[ib][jb][3] - m_new[jb]);
                psum[jb] += (p0 + p1) + (p2 + p3);
                f16x4 v4;
                v4[0] = (f16)p0; v4[1] = (f16)p1; v4[2] = (f16)p2; v4[3] = (f16)p3;
                const int jloc = 16 * jb + j16;
                const int sw   = (4 * w + 2 * ib + (h >> 1)) ^ j16;
                *(f16x4*)&Pp[jloc * 256 + sw * 8 + (h & 1) * 4] = v4;
            }
        }
#pragma unroll
        for (int jb = 0; jb < 2; ++jb) {
            psum[jb] += __shfl_xor(psum[jb], 16);
            psum[jb] += __shfl_xor(psum[jb], 32);
        }
        if (h == 0) { wsum[w][0][j16] = psum[0]; wsum[w][1][j16] = psum[1]; }

#pragma unroll
        for (int cb = 0; cb < 4; ++cb)
#pragma unroll
            for (int jb = 0; jb < 2; ++jb)
#pragma unroll
                for (int r = 0; r < 4; ++r) oacc[cb][jb][r] *= sc[jb];

        __syncthreads();

#pragma unroll
        for (int jb = 0; jb < 2; ++jb) {
            float ts = 0.f;
#pragma unroll
            for (int w2 = 0; w2 < 8; ++w2) ts += wsum[w2][jb][j16];
            l_run[jb] = l_run[jb] * sc[jb] + ts;
        }

        const int i0n = (it < 15) ? (i0 + 256) : 0;
        {
            const int irow0 = i0n + 32 * w + j16;
            fa[0][0] = *(const f16x8*)(fbase + (size_t)irow0 * CQ + 8 * h);
            fa[0][1] = *(const f16x8*)(fbase + (size_t)irow0 * CQ + 32 + 8 * h);
            fa[1][0] = *(const f16x8*)(fbase + (size_t)(irow0 + 16) * CQ + 8 * h);
            fa[1][1] = *(const f16x8*)(fbase + (size_t)(irow0 + 16) * CQ + 32 + 8 * h);
        }
        PVST(aA, 0); LDA(aA, 2, i0);
        PVST(aB, 1); LDA(aB, 3, i0);
        PVST(aA, 2); LDA(aA, 4, i0);
        PVST(aB, 3); LDA(aB, 5, i0);
        PVST(aA, 4); LDA(aA, 6, i0);
        PVST(aB, 5); LDA(aB, 7, i0);
        PVST(aA, 6); LDA(aA, 0, i0n);
        PVST(aB, 7); LDA(aB, 1, i0n);
    }

    float gam;
    if (isbf) gam = bf2f(((const u16*)gammap)[0]);
    else      gam = ((const float*)gammap)[0];

    const float inv0 = gam / l_run[0];
    const float inv1 = gam / l_run[1];

#pragma unroll
    for (int cb = 0; cb < 4; ++cb) {
#pragma unroll
        for (int jb = 0; jb < 2; ++jb) {
            const float invj = jb ? inv1 : inv0;
            const int j = j0 + 16 * jb + j16;
#pragma unroll
            for (int r = 0; r < 4; ++r) {
                const int c = 64 * w + 16 * cb + 4 * h + r;
                const size_t idx = ((size_t)b * CH + c) * NN + j;
                float xv;
                if (isbf) xv = bf2f(((const u16*)xin)[idx]);
                else      xv = ((const float*)xin)[idx];
                out[idx] = oacc[cb][jb][r] * invj + xv;
            }
        }
    }
#undef LDA
#undef PVST
}

extern "C" void kernel_launch(void* const* d_in, const int* in_sizes, int n_in,
                              void* d_out, int out_size, void* d_ws, size_t ws_size,
                              hipStream_t stream)
{
    const size_t off_l  = 256;
    const size_t off_fT = off_l  + (size_t)BATCH * NN * 4;
    const size_t off_gT = off_fT + (size_t)BATCH * NN * CQ * 2;
    const size_t off_hv = off_gT + (size_t)BATCH * NN * CQ * 2;
    const size_t off_ST = off_hv + (size_t)BATCH * CH * NN * 2;
    const size_t stN    = (size_t)NN * NN * 2;

    int*   flag = (int*)d_ws;
    float* lsum = (float*)((char*)d_ws + off_l);
    f16*   fT   = (f16*)((char*)d_ws + off_fT);
    f16*   gT   = (f16*)((char*)d_ws + off_gT);
    f16*   hv   = (f16*)((char*)d_ws + off_hv);
    f16*   ST   = (f16*)((char*)d_ws + off_ST);

    int bc = 0;
    if      (ws_size >= off_ST + 4 * stN) bc = 4;
    else if (ws_size >= off_ST + 2 * stN) bc = 2;
    else if (ws_size >= off_ST + 1 * stN) bc = 1;

    detect_kernel<<<1, 64, 0, stream>>>((const u32*)d_in[0], flag);

    dim3 pgrid(64, 10, BATCH);
    proj_kernel<<<pgrid, 256, 0, stream>>>(d_in[0], d_in[1], d_in[2], d_in[3],
                                           flag, fT, gT, hv);

    if (bc) {
        hipMemsetAsync(lsum, 0, (size_t)BATCH * NN * 4, stream);
        for (int b0 = 0; b0 < BATCH; b0 += bc) {
            dim3 g1(32, 32, bc);
            score_kernel<<<g1, 512, 0, stream>>>(fT, gT, ST, lsum, b0);
            pv_kernel<<<128 * bc, 512, 0, stream>>>(d_in[0], hv, ST, lsum,
                                                    d_in[4], flag,
                                                    (float*)d_out, b0, bc);
        }
    } else {
        attn_mfma<<<512, 512, 0, stream>>>(d_in[0], fT, gT, hv, d_in[4],
                                           flag, (float*)d_out);
    }
}

// Round 9
// 372.405 us; speedup vs baseline: 1.9893x; 1.0803x over previous
//
#include <hip/hip_runtime.h>
#include <hip/hip_bf16.h>

typedef unsigned short u16;
typedef unsigned int   u32;
typedef _Float16 f16;
typedef __attribute__((ext_vector_type(8))) _Float16 f16x8;
typedef __attribute__((ext_vector_type(4))) _Float16 f16x4;
typedef __attribute__((ext_vector_type(4))) float    f32x4;
typedef __attribute__((ext_vector_type(8))) unsigned short u16x8;

#define BATCH 4
#define CH 512
#define NN 4096
#define CQ 64
#define LOG2E 1.44269504f

__device__ __forceinline__ float bf2f(u16 v) {
    union { unsigned int u; float f; } x; x.u = ((unsigned int)v) << 16; return x.f;
}

// tiled P layout: element (j,i) -> (j>>4)*65536 + (i>>3)*128 + (j&15)*8 + (i&7)
__device__ __forceinline__ size_t stt_idx(int j, int i) {
    return (size_t)(j >> 4) * 65536 + (size_t)((i >> 3) * 128 + (j & 15) * 8 + (i & 7));
}

// ---------------------------------------------------------------------------
// Input dtype detector: 0 = fp32 inputs, 1 = bf16 inputs.
// ---------------------------------------------------------------------------
__global__ __launch_bounds__(64) void detect_kernel(const u32* __restrict__ xw,
                                                    int* __restrict__ flag)
{
    const u32 w  = xw[threadIdx.x];
    const u32 ex = (w >> 23) & 0xFFu;
    const int plausible = (ex >= 100u && ex <= 132u) ? 1 : 0;
    const unsigned long long m = __ballot(plausible);
    if (threadIdx.x == 0) flag[0] = (__popcll(m) >= 48) ? 0 : 1;
}

// ---------------------------------------------------------------------------
// W concat convert: Wc[640][512] f16 from Wq/Wk/Wv (fp32 or bf16).
// ---------------------------------------------------------------------------
__global__ __launch_bounds__(256) void wconv_kernel(
    const void* __restrict__ Wq, const void* __restrict__ Wk,
    const void* __restrict__ Wv, const int* __restrict__ flag,
    f16* __restrict__ Wc)
{
    const int isbf = *flag;
    const int row = blockIdx.x;           // 0..639
    const int t   = threadIdx.x;
    const void* src; int r;
    if (row < 64)       { src = Wq; r = row; }
    else if (row < 128) { src = Wk; r = row - 64; }
    else                { src = Wv; r = row - 128; }
    f16 v0, v1;
    if (isbf) {
        const u16* p = (const u16*)src + (size_t)r * CH + 2 * t;
        v0 = (f16)bf2f(p[0]); v1 = (f16)bf2f(p[1]);
    } else {
        const float* p = (const float*)src + (size_t)r * CH + 2 * t;
        v0 = (f16)p[0]; v1 = (f16)p[1];
    }
    Wc[(size_t)row * CH + 2 * t]     = v0;
    Wc[(size_t)row * CH + 2 * t + 1] = v1;
}

// ---------------------------------------------------------------------------
// x transpose: xT[b][n][c] f16 from x[b][c][n] (fp32 or bf16). 64x64 tiles.
// ---------------------------------------------------------------------------
__global__ __launch_bounds__(256) void xpose_kernel(
    const void* __restrict__ xin, const int* __restrict__ flag,
    f16* __restrict__ xT)
{
    const int isbf = *flag;
    const int n0 = blockIdx.x * 64, c0 = blockIdx.y * 64, b = blockIdx.z;
    const int t  = threadIdx.x;
    __shared__ float Xl[64][65];

    {
        const int row = t >> 2, nc = (t & 3) * 16;
        if (isbf) {
            const u16* p = (const u16*)xin +
                           ((size_t)(b * CH + c0 + row)) * NN + n0 + nc;
            const u16x8 a = *(const u16x8*)p;
            const u16x8 bq = *(const u16x8*)(p + 8);
#pragma unroll
            for (int i = 0; i < 8; ++i) Xl[row][nc + i]     = bf2f(a[i]);
#pragma unroll
            for (int i = 0; i < 8; ++i) Xl[row][nc + 8 + i] = bf2f(bq[i]);
        } else {
            const float* p = (const float*)xin +
                             ((size_t)(b * CH + c0 + row)) * NN + n0 + nc;
            *(float4*)&Xl[row][nc]      = ((const float4*)p)[0];
            *(float4*)&Xl[row][nc + 4]  = ((const float4*)p)[1];
            *(float4*)&Xl[row][nc + 8]  = ((const float4*)p)[2];
            *(float4*)&Xl[row][nc + 12] = ((const float4*)p)[3];
        }
    }
    __syncthreads();
    {
        const int nr = t >> 2, cc = (t & 3) * 16;
        f16x8 o0, o1;
#pragma unroll
        for (int i = 0; i < 8; ++i) o0[i] = (f16)Xl[cc + i][nr];
#pragma unroll
        for (int i = 0; i < 8; ++i) o1[i] = (f16)Xl[cc + 8 + i][nr];
        f16* dst = xT + ((size_t)b * NN + n0 + nr) * CH + c0 + cc;
        *(f16x8*)dst       = o0;
        *(f16x8*)(dst + 8) = o1;
    }
}

// ---------------------------------------------------------------------------
// Projection as all-register MFMA GEMM: out[o][n] = sum_c Wc[o][c] xT[n][c].
// Block 512 thr = 8 waves (2 ow x 4 nw); tile 128o x 128n; wave 64o x 32n.
// No LDS, no barriers: both operands k-contiguous, dist-1 reg prefetch + TLP.
//   o <  64 : -> fT[b][n][o]    o < 128 : -> gT[b][n][o-64]
//   else    : -> hv[b][o-128][n]
// ---------------------------------------------------------------------------
__global__ __launch_bounds__(512, 2) void proj_mfma(
    const f16* __restrict__ Wc, const f16* __restrict__ xT,
    f16* __restrict__ fT, f16* __restrict__ gT, f16* __restrict__ hv)
{
    const int o0 = blockIdx.x * 128;      // 0..4 -> 640 rows
    const int n0 = blockIdx.y * 128;
    const int b  = blockIdx.z;
    const int t  = threadIdx.x;
    const int w  = t >> 6, l = t & 63;
    const int j16 = l & 15, h = l >> 4;
    const int ow = w >> 2, nw = w & 3;

    const f16* wp[4];
#pragma unroll
    for (int ot = 0; ot < 4; ++ot)
        wp[ot] = Wc + (size_t)(o0 + 64 * ow + 16 * ot + j16) * CH;
    const f16* xp[2];
#pragma unroll
    for (int bt = 0; bt < 2; ++bt)
        xp[bt] = xT + ((size_t)b * NN + n0 + 32 * nw + 16 * bt + j16) * CH;

    f32x4 acc[4][2];
#pragma unroll
    for (int ot = 0; ot < 4; ++ot)
#pragma unroll
        for (int bt = 0; bt < 2; ++bt)
#pragma unroll
            for (int r = 0; r < 4; ++r) acc[ot][bt][r] = 0.f;

    f16x8 af[2][4], bq[2][2];
#pragma unroll
    for (int ot = 0; ot < 4; ++ot) af[0][ot] = *(const f16x8*)(wp[ot] + 8 * h);
#pragma unroll
    for (int bt = 0; bt < 2; ++bt) bq[0][bt] = *(const f16x8*)(xp[bt] + 8 * h);

    for (int ks = 0; ks < 16; ++ks) {
        const int cur = ks & 1;
        if (ks < 15) {
            const int k1 = (ks + 1) * 32 + 8 * h;
#pragma unroll
            for (int ot = 0; ot < 4; ++ot)
                af[cur ^ 1][ot] = *(const f16x8*)(wp[ot] + k1);
#pragma unroll
            for (int bt = 0; bt < 2; ++bt)
                bq[cur ^ 1][bt] = *(const f16x8*)(xp[bt] + k1);
        }
        __builtin_amdgcn_s_setprio(1);
#pragma unroll
        for (int ot = 0; ot < 4; ++ot)
#pragma unroll
            for (int bt = 0; bt < 2; ++bt)
                acc[ot][bt] = __builtin_amdgcn_mfma_f32_16x16x32_f16(
                                  af[cur][ot], bq[cur][bt], acc[ot][bt], 0, 0, 0);
        __builtin_amdgcn_s_setprio(0);
    }

#pragma unroll
    for (int ot = 0; ot < 4; ++ot)
#pragma unroll
        for (int bt = 0; bt < 2; ++bt)
#pragma unroll
            for (int r = 0; r < 4; ++r) {
                const int o = o0 + 64 * ow + 16 * ot + 4 * h + r;
                const int n = n0 + 32 * nw + 16 * bt + j16;
                const f16 v = (f16)acc[ot][bt][r];
                if (o < CQ) {
                    fT[((size_t)b * NN + n) * CQ + o] = v;
                } else if (o < 2 * CQ) {
                    gT[((size_t)b * NN + n) * CQ + (o - CQ)] = v;
                } else {
                    hv[((size_t)b * CH + (o - 2 * CQ)) * NN + n] = v;
                }
            }
}

// ---------------------------------------------------------------------------
// K1: per 64-i tile: m_t[j] = max_i S*log2e; P_t = exp2(S*log2e - m_t) (f16,
// tiled layout, <=1); mb[b][j][itile] = m_t; lsum[b][j] += 2^m_t * sum(P).
// ---------------------------------------------------------------------------
__global__ __launch_bounds__(512) void score_kernel(
    const f16* __restrict__ fT, const f16* __restrict__ gT,
    f16* __restrict__ ST, float* __restrict__ lsum, float* __restrict__ mb,
    int b0)
{
    const int ibk = blockIdx.x;
    const int jbk = blockIdx.y;
    const int bz  = blockIdx.z;
    const int b   = b0 + bz;
    const int t   = threadIdx.x;
    const int w   = t >> 6, l = t & 63;
    const int c16 = l & 15, h = l >> 4;
    const int wr  = w >> 1;
    const int wc  = w & 1;
    const int j0  = jbk * 128 + wr * 32;
    const int i0  = ibk * 128 + wc * 64;
    const int itile = ibk * 2 + wc;

    const f16* fb_ = fT + (size_t)b * NN * CQ;
    const f16* gb_ = gT + (size_t)b * NN * CQ;

    f16x8 ga[2][2], fbr[4][2];
#pragma unroll
    for (int ja = 0; ja < 2; ++ja)
#pragma unroll
        for (int kc = 0; kc < 2; ++kc)
            ga[ja][kc] = *(const f16x8*)(gb_ +
                (size_t)(j0 + 16 * ja + c16) * CQ + 32 * kc + 8 * h);
#pragma unroll
    for (int ii = 0; ii < 4; ++ii)
#pragma unroll
        for (int kc = 0; kc < 2; ++kc)
            fbr[ii][kc] = *(const f16x8*)(fb_ +
                (size_t)(i0 + 16 * ii + c16) * CQ + 32 * kc + 8 * h);

    f32x4 s[2][4];
#pragma unroll
    for (int ja = 0; ja < 2; ++ja)
#pragma unroll
        for (int ii = 0; ii < 4; ++ii)
#pragma unroll
            for (int r = 0; r < 4; ++r) s[ja][ii][r] = 0.f;

#pragma unroll
    for (int ja = 0; ja < 2; ++ja)
#pragma unroll
        for (int ii = 0; ii < 4; ++ii) {
            s[ja][ii] = __builtin_amdgcn_mfma_f32_16x16x32_f16(
                            ga[ja][0], fbr[ii][0], s[ja][ii], 0, 0, 0);
            s[ja][ii] = __builtin_amdgcn_mfma_f32_16x16x32_f16(
                            ga[ja][1], fbr[ii][1], s[ja][ii], 0, 0, 0);
        }

    f16* Sb = ST + (size_t)bz * NN * NN;

#pragma unroll
    for (int ja = 0; ja < 2; ++ja)
#pragma unroll
        for (int r = 0; r < 4; ++r) {
            const int jj = j0 + 16 * ja + 4 * h + r;
            float hx[4];
#pragma unroll
            for (int ii = 0; ii < 4; ++ii) hx[ii] = s[ja][ii][r] * LOG2E;
            // column (j) max over this wave's 64 i
            float mt = fmaxf(fmaxf(hx[0], hx[1]), fmaxf(hx[2], hx[3]));
            mt = fmaxf(mt, __shfl_xor(mt, 1));
            mt = fmaxf(mt, __shfl_xor(mt, 2));
            mt = fmaxf(mt, __shfl_xor(mt, 4));
            mt = fmaxf(mt, __shfl_xor(mt, 8));
            float rs = 0.f;
#pragma unroll
            for (int ii = 0; ii < 4; ++ii) {
                const float p = exp2f(hx[ii] - mt);
                rs += p;
                Sb[stt_idx(jj, i0 + 16 * ii + c16)] = (f16)p;
            }
            rs += __shfl_xor(rs, 1);
            rs += __shfl_xor(rs, 2);
            rs += __shfl_xor(rs, 4);
            rs += __shfl_xor(rs, 8);
            if (c16 == 0) {
                mb[((size_t)b * NN + jj) * 64 + itile] = mt;
                atomicAdd(&lsum[(size_t)b * NN + jj], exp2f(mt) * rs);
            }
        }
}

// ---------------------------------------------------------------------------
// K3: O = hv * (P_t .* fac)   with fac = 2^(m_t - log2 l) per (j, i-tile).
// LDS-staged GEMM (256c x 64j block, i-step 64) -- same verified skeleton as
// round 8 (bank-conflict 0), minus the per-element exp (now one pk_mul).
// ---------------------------------------------------------------------------
__global__ __launch_bounds__(512, 2) void pv_kernel(
    const void* __restrict__ xin, const f16* __restrict__ hv,
    const f16* __restrict__ ST, const float* __restrict__ lsum,
    const float* __restrict__ mb,
    const void* __restrict__ gammap, const int* __restrict__ flag,
    float* __restrict__ out, int b0, int bc)
{
    const int isbf = *flag;
    const int bid  = blockIdx.x;
    const int xcd  = bid & 7;
    const int slot = bid >> 3;
    const int perb = 8 / bc;
    const int bz   = xcd / perb;
    const int b    = b0 + bz;
    const int idx128 = (xcd % perb) * (16 * bc) + slot;
    const int jgrp = idx128 >> 1;
    const int cgrp = idx128 & 1;
    const int c0b  = cgrp * 256;

    const int t = threadIdx.x;
    const int w = t >> 6, l = t & 63;
    const int j16 = l & 15, h = l >> 4;
    const int cw = w >> 2, jw = w & 3;
    const int jt   = jgrp * 4 + jw;
    const int jcol = jt * 16 + j16;
    const int c0w  = c0b + cw * 128;

    __shared__ f16 As[2][2][16][64][8];

    const f16*   hb  = hv + (size_t)b * CH * NN;
    const f16*   Sb  = ST + (size_t)bz * NN * NN + (size_t)jt * 65536 + j16 * 8;
    const float  log2l = __log2f(lsum[(size_t)b * NN + jcol]);
    const float* mb_ = mb + ((size_t)b * NN + jcol) * 64;

    f32x4 acc[8];
#pragma unroll
    for (int ct = 0; ct < 8; ++ct)
#pragma unroll
        for (int r = 0; r < 4; ++r) acc[ct][r] = 0.f;

    f16x8 areg[4];
    f16x8 bring[4][2];
    float mring[2];

#define LD_A(I0)                                                              \
    {                                                                         \
        _Pragma("unroll")                                                     \
        for (int q = 0; q < 4; ++q) {                                         \
            const int ctl = q >> 1, ck = q & 1;                               \
            areg[q] = *(const f16x8*)(hb +                                    \
                (size_t)(c0b + (2 * w + ctl) * 16 + j16) * NN +               \
                (I0) + 32 * ck + 8 * h);                                      \
        }                                                                     \
    }

#define ST_A(BUF)                                                             \
    {                                                                         \
        _Pragma("unroll")                                                     \
        for (int q = 0; q < 4; ++q) {                                         \
            const int ctl = q >> 1, ck = q & 1;                               \
            *(f16x8*)&As[BUF][ck][2 * w + ctl][l][0] = areg[q];               \
        }                                                                     \
    }

#define LD_B(U, K)                                                            \
    {                                                                         \
        const int i0b = (K) * 64;                                             \
        bring[U][0] = *(const f16x8*)(Sb + ((i0b >> 3) + h) * 128);           \
        bring[U][1] = *(const f16x8*)(Sb + (((i0b + 32) >> 3) + h) * 128);    \
    }

    // ---- prologue ----
    LD_A(0);
    LD_B(0, 0); LD_B(1, 1); LD_B(2, 2); LD_B(3, 3);
    mring[0] = mb_[0]; mring[1] = mb_[1];
    ST_A(0);
    LD_A(64);
    asm volatile("s_waitcnt lgkmcnt(0)" ::: "memory");
    __builtin_amdgcn_s_barrier();

    for (int k4 = 0; k4 < 16; ++k4) {
#pragma unroll
        for (int u = 0; u < 4; ++u) {
            const int k   = k4 * 4 + u;
            const int cur = k & 1;

            if (k < 63) ST_A(cur ^ 1);
            if (k < 62) { const int i0p = (k + 2) * 64; LD_A(i0p); }

            const f16x8 bv0 = bring[u][0];
            const f16x8 bv1 = bring[u][1];
            { const int kk = (k + 4 <= 63) ? (k + 4) : 63; LD_B(u, kk); }

            // fac = 2^(m_t - log2 l)  (<= 1), one splat mul per frag
            const float fac32 = exp2f(mring[u & 1] - log2l);
            if (k < 62) mring[u & 1] = mb_[k + 2];
            const f16 fac = (f16)fac32;
            f16x8 fs;
#pragma unroll
            for (int e = 0; e < 8; ++e) fs[e] = fac;
            const f16x8 pb0 = bv0 * fs;
            const f16x8 pb1 = bv1 * fs;

            __builtin_amdgcn_s_setprio(1);
#pragma unroll
            for (int ct = 0; ct < 8; ++ct) {
                const f16x8 a0 = *(const f16x8*)&As[cur][0][cw * 8 + ct][l][0];
                acc[ct] = __builtin_amdgcn_mfma_f32_16x16x32_f16(a0, pb0, acc[ct], 0, 0, 0);
            }
#pragma unroll
            for (int ct = 0; ct < 8; ++ct) {
                const f16x8 a1 = *(const f16x8*)&As[cur][1][cw * 8 + ct][l][0];
                acc[ct] = __builtin_amdgcn_mfma_f32_16x16x32_f16(a1, pb1, acc[ct], 0, 0, 0);
            }
            __builtin_amdgcn_s_setprio(0);

            asm volatile("s_waitcnt lgkmcnt(0)" ::: "memory");
            __builtin_amdgcn_s_barrier();
        }
    }

    float gam;
    if (isbf) gam = bf2f(((const u16*)gammap)[0]);
    else      gam = ((const float*)gammap)[0];

#pragma unroll
    for (int ct = 0; ct < 8; ++ct)
#pragma unroll
        for (int r = 0; r < 4; ++r) {
            const int c = c0w + ct * 16 + 4 * h + r;
            const size_t idx = ((size_t)b * CH + c) * NN + jcol;
            float xv;
            if (isbf) xv = bf2f(((const u16*)xin)[idx]);
            else      xv = ((const float*)xin)[idx];
            out[idx] = gam * acc[ct][r] + xv;
        }
#undef LD_A
#undef ST_A
#undef LD_B
}

// ---------------------------------------------------------------------------
// Fallback flash kernel (round 6, passed) for small ws_size.
// ---------------------------------------------------------------------------
__global__ __launch_bounds__(512, 2) void attn_mfma(
    const void* __restrict__ xin, const f16* __restrict__ fT,
    const f16* __restrict__ gT, const f16* __restrict__ hv,
    const void* __restrict__ gammap, const int* __restrict__ flag,
    float* __restrict__ out)
{
    const int isbf = *flag;
    const int bid  = blockIdx.x;
    const int xcd  = bid & 7, slot = bid >> 3;
    const int b    = xcd >> 1;
    const int jblk = ((xcd & 1) << 6) + slot;
    const int j0   = jblk * 32;
    const int t    = threadIdx.x;
    const int w    = t >> 6;
    const int l    = t & 63;
    const int j16  = l & 15;
    const int h    = l >> 4;

    __shared__ f16   Pp[32 * 256];
    __shared__ float wmax[8][2][16];
    __shared__ float wsum[8][2][16];

    f16x8 gf[2][2];
#pragma unroll
    for (int jb = 0; jb < 2; ++jb)
#pragma unroll
        for (int kc = 0; kc < 2; ++kc)
            gf[jb][kc] = *(const f16x8*)(gT +
                ((size_t)b * NN + j0 + 16 * jb + j16) * CQ + 32 * kc + 8 * h);

    f32x4 oacc[4][2];
#pragma unroll
    for (int cb = 0; cb < 4; ++cb)
#pragma unroll
        for (int jb = 0; jb < 2; ++jb)
#pragma unroll
            for (int r = 0; r < 4; ++r) oacc[cb][jb][r] = 0.f;

    float m_run[2] = {-1e30f, -1e30f};
    float l_run[2] = {0.f, 0.f};

    const f16* fbase = fT + (size_t)b * NN * CQ;
    const f16* hbase = hv + (size_t)b * CH * NN;

    f16x8 fa[2][2];
    {
        const int irow0 = 32 * w + j16;
        fa[0][0] = *(const f16x8*)(fbase + (size_t)irow0 * CQ + 8 * h);
        fa[0][1] = *(const f16x8*)(fbase + (size_t)irow0 * CQ + 32 + 8 * h);
        fa[1][0] = *(const f16x8*)(fbase + (size_t)(irow0 + 16) * CQ + 8 * h);
        fa[1][1] = *(const f16x8*)(fbase + (size_t)(irow0 + 16) * CQ + 32 + 8 * h);
    }
    f16x8 aA[4], aB[4];

#define LDA(BUF, KC, I0BASE)                                                  \
    {                                                                         \
        _Pragma("unroll")                                                     \
        for (int cb = 0; cb < 4; ++cb)                                        \
            BUF[cb] = *(const f16x8*)(hbase +                                 \
                (size_t)(64 * w + 16 * cb + j16) * NN +                       \
                (I0BASE) + 32 * (KC) + 8 * h);                                \
    }

#define PVST(BUF, KC)                                                         \
    {                                                                         \
        const int sw0 = (4 * (KC) + h) ^ j16;                                 \
        const f16x8 pf0 = *(const f16x8*)&Pp[j16 * 256 + sw0 * 8];            \
        const f16x8 pf1 = *(const f16x8*)&Pp[(16 + j16) * 256 + sw0 * 8];     \
        _Pragma("unroll")                                                     \
        for (int cb = 0; cb < 4; ++cb) {                                      \
            oacc[cb][0] = __builtin_amdgcn_mfma_f32_16x16x32_f16(             \
                              BUF[cb], pf0, oacc[cb][0], 0, 0, 0);            \
            oacc[cb][1] = __builtin_amdgcn_mfma_f32_16x16x32_f16(             \
                              BUF[cb], pf1, oacc[cb][1], 0, 0, 0);            \
        }                                                                     \
    }

    LDA(aA, 0, 0);
    LDA(aB, 1, 0);

    for (int it = 0; it < 16; ++it) {
        const int i0 = it * 256;

        f32x4 s[2][2];
#pragma unroll
        for (int ib = 0; ib < 2; ++ib)
#pragma unroll
            for (int jb = 0; jb < 2; ++jb)
#pragma unroll
                for (int r = 0; r < 4; ++r) s[ib][jb][r] = 0.f;

#pragma unroll
        for (int ib = 0; ib < 2; ++ib)
#pragma unroll
            for (int jb = 0; jb < 2; ++jb) {
                s[ib][jb] = __builtin_amdgcn_mfma_f32_16x16x32_f16(
                                fa[ib][0], gf[jb][0], s[ib][jb], 0, 0, 0);
                s[ib][jb] = __builtin_amdgcn_mfma_f32_16x16x32_f16(
                                fa[ib][1], gf[jb][1], s[ib][jb], 0, 0, 0);
            }

        float pmax[2];
#pragma unroll
        for (int jb = 0; jb < 2; ++jb) {
            float m0 = fmaxf(fmaxf(s[0][jb][0], s[0][jb][1]),
                             fmaxf(s[0][jb][2], s[0][jb][3]));
            float m1 = fmaxf(fmaxf(s[1][jb][0], s[1][jb][1]),
                             fmaxf(s[1][jb][2], s[1][jb][3]));
            float mm = fmaxf(m0, m1);
            mm = fmaxf(mm, __shfl_xor(mm, 16));
            mm = fmaxf(mm, __shfl_xor(mm, 32));
            pmax[jb] = mm;
        }
        if (h == 0) { wmax[w][0][j16] = pmax[0]; wmax[w][1][j16] = pmax[1]; }
        __syncthreads();

        float m_new[2], sc[2];
#pragma unroll
        for (int jb = 0; jb < 2; ++jb) {
            float tm = wmax[0][jb][j16];
#pragma unroll
            for (int w2 = 1; w2 < 8; ++w2) tm = fmaxf(tm, wmax[w2][jb][j16]);
            m_new[jb] = fmaxf(m_run[jb], tm);
            sc[jb]    = __expf(m_run[jb] - m_new[jb]);
            m_run[jb] = m_new[jb];
        }

        float psum[2] = {0.f, 0.f};
#pragma unroll
        for (int ib = 0; ib < 2; ++ib) {
#pragma unroll
            for (int jb = 0; jb < 2; ++jb) {
                const float p0 = __expf(s[ib][jb][0] - m_new[jb]);
                const float p1 = __expf(s[ib][jb][1] - m_new[jb]);
                const float p2 = __expf(s[ib][jb][2] - m_new[jb]);
                const float p3 = __expf(s[ib][jb][3] - m_new[jb]);
                psum[jb] += (p0 + p1) + (p2 + p3);
                f16x4 v4;
                v4[0] = (f16)p0; v4[1] = (f16)p1; v4[2] = (f16)p2; v4[3] = (f16)p3;
                const int jloc = 16 * jb + j16;
                const int sw   = (4 * w + 2 * ib + (h >> 1)) ^ j16;
                *(f16x4*)&Pp[jloc * 256 + sw * 8 + (h & 1) * 4] = v4;
            }
        }
#pragma unroll
        for (int jb = 0; jb < 2; ++jb) {
            psum[jb] += __shfl_xor(psum[jb], 16);
            psum[jb] += __shfl_xor(psum[jb], 32);
        }
        if (h == 0) { wsum[w][0][j16] = psum[0]; wsum[w][1][j16] = psum[1]; }

#pragma unroll
        for (int cb = 0; cb < 4; ++cb)
#pragma unroll
            for (int jb = 0; jb < 2; ++jb)
#pragma unroll
                for (int r = 0; r < 4; ++r) oacc[cb][jb][r] *= sc[jb];

        __syncthreads();

#pragma unroll
        for (int jb = 0; jb < 2; ++jb) {
            float ts = 0.f;
#pragma unroll
            for (int w2 = 0; w2 < 8; ++w2) ts += wsum[w2][jb][j16];
            l_run[jb] = l_run[jb] * sc[jb] + ts;
        }

        const int i0n = (it < 15) ? (i0 + 256) : 0;
        {
            const int irow0 = i0n + 32 * w + j16;
            fa[0][0] = *(const f16x8*)(fbase + (size_t)irow0 * CQ + 8 * h);
            fa[0][1] = *(const f16x8*)(fbase + (size_t)irow0 * CQ + 32 + 8 * h);
            fa[1][0] = *(const f16x8*)(fbase + (size_t)(irow0 + 16) * CQ + 8 * h);
            fa[1][1] = *(const f16x8*)(fbase + (size_t)(irow0 + 16) * CQ + 32 + 8 * h);
        }
        PVST(aA, 0); LDA(aA, 2, i0);
        PVST(aB, 1); LDA(aB, 3, i0);
        PVST(aA, 2); LDA(aA, 4, i0);
        PVST(aB, 3); LDA(aB, 5, i0);
        PVST(aA, 4); LDA(aA, 6, i0);
        PVST(aB, 5); LDA(aB, 7, i0);
        PVST(aA, 6); LDA(aA, 0, i0n);
        PVST(aB, 7); LDA(aB, 1, i0n);
    }

    float gam;
    if (isbf) gam = bf2f(((const u16*)gammap)[0]);
    else      gam = ((const float*)gammap)[0];

    const float inv0 = gam / l_run[0];
    const float inv1 = gam / l_run[1];

#pragma unroll
    for (int cb = 0; cb < 4; ++cb) {
#pragma unroll
        for (int jb = 0; jb < 2; ++jb) {
            const float invj = jb ? inv1 : inv0;
            const int j = j0 + 16 * jb + j16;
#pragma unroll
            for (int r = 0; r < 4; ++r) {
                const int c = 64 * w + 16 * cb + 4 * h + r;
                const size_t idx = ((size_t)b * CH + c) * NN + j;
                float xv;
                if (isbf) xv = bf2f(((const u16*)xin)[idx]);
                else      xv = ((const float*)xin)[idx];
                out[idx] = oacc[cb][jb][r] * invj + xv;
            }
        }
    }
#undef LDA
#undef PVST
}

extern "C" void kernel_launch(void* const* d_in, const int* in_sizes, int n_in,
                              void* d_out, int out_size, void* d_ws, size_t ws_size,
                              hipStream_t stream)
{
    const size_t off_l  = 256;
    const size_t off_m  = off_l  + (size_t)BATCH * NN * 4;          // lsum 64KB
    const size_t off_fT = off_m  + (size_t)BATCH * NN * 64 * 4;     // mb 4MB
    const size_t off_gT = off_fT + (size_t)BATCH * NN * CQ * 2;
    const size_t off_hv = off_gT + (size_t)BATCH * NN * CQ * 2;
    const size_t off_xT = off_hv + (size_t)BATCH * CH * NN * 2;
    const size_t off_Wc = off_xT + (size_t)BATCH * NN * CH * 2;     // xT 16MB
    const size_t off_ST = off_Wc + (size_t)640 * CH * 2;            // Wc 0.66MB
    const size_t stN    = (size_t)NN * NN * 2;

    int*   flag = (int*)d_ws;
    float* lsum = (float*)((char*)d_ws + off_l);
    float* mb   = (float*)((char*)d_ws + off_m);
    f16*   fT   = (f16*)((char*)d_ws + off_fT);
    f16*   gT   = (f16*)((char*)d_ws + off_gT);
    f16*   hv   = (f16*)((char*)d_ws + off_hv);
    f16*   xT   = (f16*)((char*)d_ws + off_xT);
    f16*   Wc   = (f16*)((char*)d_ws + off_Wc);
    f16*   ST   = (f16*)((char*)d_ws + off_ST);

    int bc = 0;
    if      (ws_size >= off_ST + 4 * stN) bc = 4;
    else if (ws_size >= off_ST + 2 * stN) bc = 2;
    else if (ws_size >= off_ST + 1 * stN) bc = 1;

    detect_kernel<<<1, 64, 0, stream>>>((const u32*)d_in[0], flag);
    wconv_kernel<<<640, 256, 0, stream>>>(d_in[1], d_in[2], d_in[3], flag, Wc);
    xpose_kernel<<<dim3(64, 8, BATCH), 256, 0, stream>>>(d_in[0], flag, xT);
    proj_mfma<<<dim3(5, 32, BATCH), 512, 0, stream>>>(Wc, xT, fT, gT, hv);

    if (bc) {
        hipMemsetAsync(lsum, 0, (size_t)BATCH * NN * 4, stream);
        for (int b0 = 0; b0 < BATCH; b0 += bc) {
            dim3 g1(32, 32, bc);
            score_kernel<<<g1, 512, 0, stream>>>(fT, gT, ST, lsum, mb, b0);
            pv_kernel<<<128 * bc, 512, 0, stream>>>(d_in[0], hv, ST, lsum, mb,
                                                    d_in[4], flag,
                                                    (float*)d_out, b0, bc);
        }
    } else {
        attn_mfma<<<512, 512, 0, stream>>>(d_in[0], fT, gT, hv, d_in[4],
                                           flag, (float*)d_out);
    }
}

// Round 10
// 344.058 us; speedup vs baseline: 2.1532x; 1.0824x over previous
//
#include <hip/hip_runtime.h>
#include <hip/hip_bf16.h>

typedef unsigned short u16;
typedef unsigned int   u32;
typedef _Float16 f16;
typedef __attribute__((ext_vector_type(8))) _Float16 f16x8;
typedef __attribute__((ext_vector_type(4))) _Float16 f16x4;
typedef __attribute__((ext_vector_type(4))) float    f32x4;
typedef __attribute__((ext_vector_type(8))) unsigned short u16x8;

#define BATCH 4
#define CH 512
#define NN 4096
#define CQ 64
#define LOG2E 1.44269504f

__device__ __forceinline__ float bf2f(u16 v) {
    union { unsigned int u; float f; } x; x.u = ((unsigned int)v) << 16; return x.f;
}

// tiled P layout: element (j,i) -> (j>>4)*65536 + (i>>3)*128 + (j&15)*8 + (i&7)
__device__ __forceinline__ size_t stt_idx(int j, int i) {
    return (size_t)(j >> 4) * 65536 + (size_t)((i >> 3) * 128 + (j & 15) * 8 + (i & 7));
}

// ---------------------------------------------------------------------------
// Input dtype detector: 0 = fp32 inputs, 1 = bf16 inputs.
// ---------------------------------------------------------------------------
__global__ __launch_bounds__(64) void detect_kernel(const u32* __restrict__ xw,
                                                    int* __restrict__ flag)
{
    const u32 w  = xw[threadIdx.x];
    const u32 ex = (w >> 23) & 0xFFu;
    const int plausible = (ex >= 100u && ex <= 132u) ? 1 : 0;
    const unsigned long long m = __ballot(plausible);
    if (threadIdx.x == 0) flag[0] = (__popcll(m) >= 48) ? 0 : 1;
}

// ---------------------------------------------------------------------------
// W concat convert: Wc[640][512] f16 from Wq/Wk/Wv (fp32 or bf16).
// ---------------------------------------------------------------------------
__global__ __launch_bounds__(256) void wconv_kernel(
    const void* __restrict__ Wq, const void* __restrict__ Wk,
    const void* __restrict__ Wv, const int* __restrict__ flag,
    f16* __restrict__ Wc)
{
    const int isbf = *flag;
    const int row = blockIdx.x;           // 0..639
    const int t   = threadIdx.x;
    const void* src; int r;
    if (row < 64)       { src = Wq; r = row; }
    else if (row < 128) { src = Wk; r = row - 64; }
    else                { src = Wv; r = row - 128; }
    f16 v0, v1;
    if (isbf) {
        const u16* p = (const u16*)src + (size_t)r * CH + 2 * t;
        v0 = (f16)bf2f(p[0]); v1 = (f16)bf2f(p[1]);
    } else {
        const float* p = (const float*)src + (size_t)r * CH + 2 * t;
        v0 = (f16)p[0]; v1 = (f16)p[1];
    }
    Wc[(size_t)row * CH + 2 * t]     = v0;
    Wc[(size_t)row * CH + 2 * t + 1] = v1;
}

// ---------------------------------------------------------------------------
// x transpose: xT[b][n][c] f16 from x[b][c][n] (fp32 or bf16). 64x64 tiles.
// ---------------------------------------------------------------------------
__global__ __launch_bounds__(256) void xpose_kernel(
    const void* __restrict__ xin, const int* __restrict__ flag,
    f16* __restrict__ xT)
{
    const int isbf = *flag;
    const int n0 = blockIdx.x * 64, c0 = blockIdx.y * 64, b = blockIdx.z;
    const int t  = threadIdx.x;
    __shared__ float Xl[64][65];

    {
        const int row = t >> 2, nc = (t & 3) * 16;
        if (isbf) {
            const u16* p = (const u16*)xin +
                           ((size_t)(b * CH + c0 + row)) * NN + n0 + nc;
            const u16x8 a = *(const u16x8*)p;
            const u16x8 bq = *(const u16x8*)(p + 8);
#pragma unroll
            for (int i = 0; i < 8; ++i) Xl[row][nc + i]     = bf2f(a[i]);
#pragma unroll
            for (int i = 0; i < 8; ++i) Xl[row][nc + 8 + i] = bf2f(bq[i]);
        } else {
            const float* p = (const float*)xin +
                             ((size_t)(b * CH + c0 + row)) * NN + n0 + nc;
            *(float4*)&Xl[row][nc]      = ((const float4*)p)[0];
            *(float4*)&Xl[row][nc + 4]  = ((const float4*)p)[1];
            *(float4*)&Xl[row][nc + 8]  = ((const float4*)p)[2];
            *(float4*)&Xl[row][nc + 12] = ((const float4*)p)[3];
        }
    }
    __syncthreads();
    {
        const int nr = t >> 2, cc = (t & 3) * 16;
        f16x8 o0, o1;
#pragma unroll
        for (int i = 0; i < 8; ++i) o0[i] = (f16)Xl[cc + i][nr];
#pragma unroll
        for (int i = 0; i < 8; ++i) o1[i] = (f16)Xl[cc + 8 + i][nr];
        f16* dst = xT + ((size_t)b * NN + n0 + nr) * CH + c0 + cc;
        *(f16x8*)dst       = o0;
        *(f16x8*)(dst + 8) = o1;
    }
}

// ---------------------------------------------------------------------------
// Projection as all-register MFMA GEMM: out[o][n] = sum_c Wc[o][c] xT[n][c].
// ---------------------------------------------------------------------------
__global__ __launch_bounds__(512, 2) void proj_mfma(
    const f16* __restrict__ Wc, const f16* __restrict__ xT,
    f16* __restrict__ fT, f16* __restrict__ gT, f16* __restrict__ hv)
{
    const int o0 = blockIdx.x * 128;      // 0..4 -> 640 rows
    const int n0 = blockIdx.y * 128;
    const int b  = blockIdx.z;
    const int t  = threadIdx.x;
    const int w  = t >> 6, l = t & 63;
    const int j16 = l & 15, h = l >> 4;
    const int ow = w >> 2, nw = w & 3;

    const f16* wp[4];
#pragma unroll
    for (int ot = 0; ot < 4; ++ot)
        wp[ot] = Wc + (size_t)(o0 + 64 * ow + 16 * ot + j16) * CH;
    const f16* xp[2];
#pragma unroll
    for (int bt = 0; bt < 2; ++bt)
        xp[bt] = xT + ((size_t)b * NN + n0 + 32 * nw + 16 * bt + j16) * CH;

    f32x4 acc[4][2];
#pragma unroll
    for (int ot = 0; ot < 4; ++ot)
#pragma unroll
        for (int bt = 0; bt < 2; ++bt)
#pragma unroll
            for (int r = 0; r < 4; ++r) acc[ot][bt][r] = 0.f;

    f16x8 af[2][4], bq[2][2];
#pragma unroll
    for (int ot = 0; ot < 4; ++ot) af[0][ot] = *(const f16x8*)(wp[ot] + 8 * h);
#pragma unroll
    for (int bt = 0; bt < 2; ++bt) bq[0][bt] = *(const f16x8*)(xp[bt] + 8 * h);

    for (int ks = 0; ks < 16; ++ks) {
        const int cur = ks & 1;
        if (ks < 15) {
            const int k1 = (ks + 1) * 32 + 8 * h;
#pragma unroll
            for (int ot = 0; ot < 4; ++ot)
                af[cur ^ 1][ot] = *(const f16x8*)(wp[ot] + k1);
#pragma unroll
            for (int bt = 0; bt < 2; ++bt)
                bq[cur ^ 1][bt] = *(const f16x8*)(xp[bt] + k1);
        }
        __builtin_amdgcn_s_setprio(1);
#pragma unroll
        for (int ot = 0; ot < 4; ++ot)
#pragma unroll
            for (int bt = 0; bt < 2; ++bt)
                acc[ot][bt] = __builtin_amdgcn_mfma_f32_16x16x32_f16(
                                  af[cur][ot], bq[cur][bt], acc[ot][bt], 0, 0, 0);
        __builtin_amdgcn_s_setprio(0);
    }

#pragma unroll
    for (int ot = 0; ot < 4; ++ot)
#pragma unroll
        for (int bt = 0; bt < 2; ++bt)
#pragma unroll
            for (int r = 0; r < 4; ++r) {
                const int o = o0 + 64 * ow + 16 * ot + 4 * h + r;
                const int n = n0 + 32 * nw + 16 * bt + j16;
                const f16 v = (f16)acc[ot][bt][r];
                if (o < CQ) {
                    fT[((size_t)b * NN + n) * CQ + o] = v;
                } else if (o < 2 * CQ) {
                    gT[((size_t)b * NN + n) * CQ + (o - CQ)] = v;
                } else {
                    hv[((size_t)b * CH + (o - 2 * CQ)) * NN + n] = v;
                }
            }
}

// ---------------------------------------------------------------------------
// K1: per 64-i tile: m_t[j] = max_i S*log2e; P_t = exp2(S*log2e - m_t) (f16,
// tiled layout, <=1); mb[b][j][itile] = m_t; lsum[b][j] += 2^m_t * sum(P).
// ---------------------------------------------------------------------------
__global__ __launch_bounds__(512) void score_kernel(
    const f16* __restrict__ fT, const f16* __restrict__ gT,
    f16* __restrict__ ST, float* __restrict__ lsum, float* __restrict__ mb,
    int b0)
{
    const int ibk = blockIdx.x;
    const int jbk = blockIdx.y;
    const int bz  = blockIdx.z;
    const int b   = b0 + bz;
    const int t   = threadIdx.x;
    const int w   = t >> 6, l = t & 63;
    const int c16 = l & 15, h = l >> 4;
    const int wr  = w >> 1;
    const int wc  = w & 1;
    const int j0  = jbk * 128 + wr * 32;
    const int i0  = ibk * 128 + wc * 64;
    const int itile = ibk * 2 + wc;

    const f16* fb_ = fT + (size_t)b * NN * CQ;
    const f16* gb_ = gT + (size_t)b * NN * CQ;

    f16x8 ga[2][2], fbr[4][2];
#pragma unroll
    for (int ja = 0; ja < 2; ++ja)
#pragma unroll
        for (int kc = 0; kc < 2; ++kc)
            ga[ja][kc] = *(const f16x8*)(gb_ +
                (size_t)(j0 + 16 * ja + c16) * CQ + 32 * kc + 8 * h);
#pragma unroll
    for (int ii = 0; ii < 4; ++ii)
#pragma unroll
        for (int kc = 0; kc < 2; ++kc)
            fbr[ii][kc] = *(const f16x8*)(fb_ +
                (size_t)(i0 + 16 * ii + c16) * CQ + 32 * kc + 8 * h);

    f32x4 s[2][4];
#pragma unroll
    for (int ja = 0; ja < 2; ++ja)
#pragma unroll
        for (int ii = 0; ii < 4; ++ii)
#pragma unroll
            for (int r = 0; r < 4; ++r) s[ja][ii][r] = 0.f;

#pragma unroll
    for (int ja = 0; ja < 2; ++ja)
#pragma unroll
        for (int ii = 0; ii < 4; ++ii) {
            s[ja][ii] = __builtin_amdgcn_mfma_f32_16x16x32_f16(
                            ga[ja][0], fbr[ii][0], s[ja][ii], 0, 0, 0);
            s[ja][ii] = __builtin_amdgcn_mfma_f32_16x16x32_f16(
                            ga[ja][1], fbr[ii][1], s[ja][ii], 0, 0, 0);
        }

    f16* Sb = ST + (size_t)bz * NN * NN;

#pragma unroll
    for (int ja = 0; ja < 2; ++ja)
#pragma unroll
        for (int r = 0; r < 4; ++r) {
            const int jj = j0 + 16 * ja + 4 * h + r;
            float hx[4];
#pragma unroll
            for (int ii = 0; ii < 4; ++ii) hx[ii] = s[ja][ii][r] * LOG2E;
            float mt = fmaxf(fmaxf(hx[0], hx[1]), fmaxf(hx[2], hx[3]));
            mt = fmaxf(mt, __shfl_xor(mt, 1));
            mt = fmaxf(mt, __shfl_xor(mt, 2));
            mt = fmaxf(mt, __shfl_xor(mt, 4));
            mt = fmaxf(mt, __shfl_xor(mt, 8));
            float rs = 0.f;
#pragma unroll
            for (int ii = 0; ii < 4; ++ii) {
                const float p = exp2f(hx[ii] - mt);
                rs += p;
                Sb[stt_idx(jj, i0 + 16 * ii + c16)] = (f16)p;
            }
            rs += __shfl_xor(rs, 1);
            rs += __shfl_xor(rs, 2);
            rs += __shfl_xor(rs, 4);
            rs += __shfl_xor(rs, 8);
            if (c16 == 0) {
                mb[((size_t)b * NN + jj) * 64 + itile] = mt;
                atomicAdd(&lsum[(size_t)b * NN + jj], exp2f(mt) * rs);
            }
        }
}

// ---------------------------------------------------------------------------
// K3 (restructured): O = hv * (P_t .* fac).
// Block = 8 waves (512 thr) covering 256c x 64j; i-step 64.
// Wave w owns c-slice [c0b+32w, +32): A (hv) direct from L2, per-wave,
// ZERO duplication, no LDS for A. Only B (P tile, 8 KB/step) is LDS-staged
// (16 KB dbuf), fac applied at stage time (1 exp2 + 1 splat-mul per thread).
// Per step per wave: 1 ds_write + 8 ds_read + 16 MFMA.
// ---------------------------------------------------------------------------
__global__ __launch_bounds__(512, 2) void pv_kernel(
    const void* __restrict__ xin, const f16* __restrict__ hv,
    const f16* __restrict__ ST, const float* __restrict__ lsum,
    const float* __restrict__ mb,
    const void* __restrict__ gammap, const int* __restrict__ flag,
    float* __restrict__ out, int b0, int bc)
{
    const int isbf = *flag;
    const int bid  = blockIdx.x;
    const int xcd  = bid & 7;
    const int slot = bid >> 3;
    const int perb = 8 / bc;
    const int bz   = xcd / perb;
    const int b    = b0 + bz;
    const int idx128 = (xcd % perb) * (16 * bc) + slot;
    const int jgrp = idx128 >> 1;           // 0..63
    const int cgrp = idx128 & 1;
    const int c0b  = cgrp * 256;

    const int t = threadIdx.x;
    const int w = t >> 6, l = t & 63;
    const int j16 = l & 15, h = l >> 4;

    // staging role: thread t stages the B-fragment word [jt_s][ck_s][l]
    const int jt_s = t >> 7;                // 0..3
    const int ck_s = (t >> 6) & 1;          // 0..1

    __shared__ f16 Bs[2][4][2][64][8];      // 16 KB double-buffered P tile

    const f16* hb  = hv + (size_t)b * CH * NN;
    const f16* SbS = ST + (size_t)bz * NN * NN
                   + (size_t)(jgrp * 4 + jt_s) * 65536 + j16 * 8;
    const int   jfac  = jgrp * 64 + jt_s * 16 + j16;   // staged element's j
    const float log2l = __log2f(lsum[(size_t)b * NN + jfac]);
    const float* mbp  = mb + ((size_t)b * NN + jfac) * 64;

    f32x4 acc[2][4];                        // [ct][jt]
#pragma unroll
    for (int ct = 0; ct < 2; ++ct)
#pragma unroll
        for (int jt = 0; jt < 4; ++jt)
#pragma unroll
            for (int r = 0; r < 4; ++r) acc[ct][jt][r] = 0.f;

    f16x8 Ar[2][4];                         // A ring [parity][ct*2+ck]
    f16x8 breg[2];                          // B global ring
    float mreg[2];                          // mb ring

#define LDA(P, K)                                                             \
    {                                                                         \
        const int i0_ = (K) * 64;                                             \
        _Pragma("unroll")                                                     \
        for (int q = 0; q < 4; ++q) {                                         \
            const int ct = q >> 1, ck = q & 1;                                \
            Ar[P][q] = *(const f16x8*)(hb +                                   \
                (size_t)(c0b + 32 * w + 16 * ct + j16) * NN +                 \
                i0_ + 32 * ck + 8 * h);                                       \
        }                                                                     \
    }

#define LDB(P, K)                                                             \
    {                                                                         \
        breg[P] = *(const f16x8*)(SbS + ((K) * 8 + 4 * ck_s + h) * 128);      \
        mreg[P] = mbp[K];                                                     \
    }

#define STB(BUF, P)                                                           \
    {                                                                         \
        const f16 fc = (f16)exp2f(mreg[P] - log2l);                           \
        f16x8 fs;                                                             \
        _Pragma("unroll") for (int e = 0; e < 8; ++e) fs[e] = fc;             \
        *(f16x8*)&Bs[BUF][jt_s][ck_s][l][0] = breg[P] * fs;                   \
    }

    // ---- prologue ----
    LDB(0, 0); LDB(1, 1);
    LDA(0, 0); LDA(1, 1);
    STB(0, 0);                              // stage buf0 (step 0)
    asm volatile("s_waitcnt lgkmcnt(0)" ::: "memory");
    __builtin_amdgcn_s_barrier();

    for (int k4 = 0; k4 < 16; ++k4) {
#pragma unroll
        for (int u = 0; u < 4; ++u) {
            const int k   = k4 * 4 + u;
            const int cur = k & 1;

            // 1) stage P tile for step k+1 (uses breg[cur^1], loaded step k-1)
            if (k < 63) STB(cur ^ 1, cur ^ 1);
            // 2) issue B global + mb for step k+2
            if (k < 62) LDB(cur, k + 2);

            // 3) MFMA from Bs[cur] (LDS) and Ar[cur] (registers)
#pragma unroll
            for (int ck = 0; ck < 2; ++ck) {
                f16x8 bf[4];
#pragma unroll
                for (int jt = 0; jt < 4; ++jt)
                    bf[jt] = *(const f16x8*)&Bs[cur][jt][ck][l][0];
                __builtin_amdgcn_s_setprio(1);
#pragma unroll
                for (int ct = 0; ct < 2; ++ct)
#pragma unroll
                    for (int jt = 0; jt < 4; ++jt)
                        acc[ct][jt] = __builtin_amdgcn_mfma_f32_16x16x32_f16(
                            Ar[cur][ct * 2 + ck], bf[jt], acc[ct][jt], 0, 0, 0);
                __builtin_amdgcn_s_setprio(0);
            }

            // 4) issue A for step k+2 (Ar[cur] free after the MFMAs above)
            if (k < 62) LDA(cur, k + 2);

            // 5) buffer swap sync
            asm volatile("s_waitcnt lgkmcnt(0)" ::: "memory");
            __builtin_amdgcn_s_barrier();
        }
    }

    // ---- epilogue: out = gamma * acc + x ----
    float gam;
    if (isbf) gam = bf2f(((const u16*)gammap)[0]);
    else      gam = ((const float*)gammap)[0];

#pragma unroll
    for (int ct = 0; ct < 2; ++ct)
#pragma unroll
        for (int jt = 0; jt < 4; ++jt)
#pragma unroll
            for (int r = 0; r < 4; ++r) {
                const int c = c0b + 32 * w + 16 * ct + 4 * h + r;
                const int j = jgrp * 64 + 16 * jt + j16;
                const size_t idx = ((size_t)b * CH + c) * NN + j;
                float xv;
                if (isbf) xv = bf2f(((const u16*)xin)[idx]);
                else      xv = ((const float*)xin)[idx];
                out[idx] = gam * acc[ct][jt][r] + xv;
            }
#undef LDA
#undef LDB
#undef STB
}

// ---------------------------------------------------------------------------
// Fallback flash kernel (round 6, passed) for small ws_size.
// ---------------------------------------------------------------------------
__global__ __launch_bounds__(512, 2) void attn_mfma(
    const void* __restrict__ xin, const f16* __restrict__ fT,
    const f16* __restrict__ gT, const f16* __restrict__ hv,
    const void* __restrict__ gammap, const int* __restrict__ flag,
    float* __restrict__ out)
{
    const int isbf = *flag;
    const int bid  = blockIdx.x;
    const int xcd  = bid & 7, slot = bid >> 3;
    const int b    = xcd >> 1;
    const int jblk = ((xcd & 1) << 6) + slot;
    const int j0   = jblk * 32;
    const int t    = threadIdx.x;
    const int w    = t >> 6;
    const int l    = t & 63;
    const int j16  = l & 15;
    const int h    = l >> 4;

    __shared__ f16   Pp[32 * 256];
    __shared__ float wmax[8][2][16];
    __shared__ float wsum[8][2][16];

    f16x8 gf[2][2];
#pragma unroll
    for (int jb = 0; jb < 2; ++jb)
#pragma unroll
        for (int kc = 0; kc < 2; ++kc)
            gf[jb][kc] = *(const f16x8*)(gT +
                ((size_t)b * NN + j0 + 16 * jb + j16) * CQ + 32 * kc + 8 * h);

    f32x4 oacc[4][2];
#pragma unroll
    for (int cb = 0; cb < 4; ++cb)
#pragma unroll
        for (int jb = 0; jb < 2; ++jb)
#pragma unroll
            for (int r = 0; r < 4; ++r) oacc[cb][jb][r] = 0.f;

    float m_run[2] = {-1e30f, -1e30f};
    float l_run[2] = {0.f, 0.f};

    const f16* fbase = fT + (size_t)b * NN * CQ;
    const f16* hbase = hv + (size_t)b * CH * NN;

    f16x8 fa[2][2];
    {
        const int irow0 = 32 * w + j16;
        fa[0][0] = *(const f16x8*)(fbase + (size_t)irow0 * CQ + 8 * h);
        fa[0][1] = *(const f16x8*)(fbase + (size_t)irow0 * CQ + 32 + 8 * h);
        fa[1][0] = *(const f16x8*)(fbase + (size_t)(irow0 + 16) * CQ + 8 * h);
        fa[1][1] = *(const f16x8*)(fbase + (size_t)(irow0 + 16) * CQ + 32 + 8 * h);
    }
    f16x8 aA[4], aB[4];

#define LDAF(BUF, KC, I0BASE)                                                 \
    {                                                                         \
        _Pragma("unroll")                                                     \
        for (int cb = 0; cb < 4; ++cb)                                        \
            BUF[cb] = *(const f16x8*)(hbase +                                 \
                (size_t)(64 * w + 16 * cb + j16) * NN +                       \
                (I0BASE) + 32 * (KC) + 8 * h);                                \
    }

#define PVSTF(BUF, KC)                                                        \
    {                                                                         \
        const int sw0 = (4 * (KC) + h) ^ j16;                                 \
        const f16x8 pf0 = *(const f16x8*)&Pp[j16 * 256 + sw0 * 8];            \
        const f16x8 pf1 = *(const f16x8*)&Pp[(16 + j16) * 256 + sw0 * 8];     \
        _Pragma("unroll")                                                     \
        for (int cb = 0; cb < 4; ++cb) {                                      \
            oacc[cb][0] = __builtin_amdgcn_mfma_f32_16x16x32_f16(             \
                              BUF[cb], pf0, oacc[cb][0], 0, 0, 0);            \
            oacc[cb][1] = __builtin_amdgcn_mfma_f32_16x16x32_f16(             \
                              BUF[cb], pf1, oacc[cb][1], 0, 0, 0);            \
        }                                                                     \
    }

    LDAF(aA, 0, 0);
    LDAF(aB, 1, 0);

    for (int it = 0; it < 16; ++it) {
        const int i0 = it * 256;

        f32x4 s[2][2];
#pragma unroll
        for (int ib = 0; ib < 2; ++ib)
#pragma unroll
            for (int jb = 0; jb < 2; ++jb)
#pragma unroll
                for (int r = 0; r < 4; ++r) s[ib][jb][r] = 0.f;

#pragma unroll
        for (int ib = 0; ib < 2; ++ib)
#pragma unroll
            for (int jb = 0; jb < 2; ++jb) {
                s[ib][jb] = __builtin_amdgcn_mfma_f32_16x16x32_f16(
                                fa[ib][0], gf[jb][0], s[ib][jb], 0, 0, 0);
                s[ib][jb] = __builtin_amdgcn_mfma_f32_16x16x32_f16(
                                fa[ib][1], gf[jb][1], s[ib][jb], 0, 0, 0);
            }

        float pmax[2];
#pragma unroll
        for (int jb = 0; jb < 2; ++jb) {
            float m0 = fmaxf(fmaxf(s[0][jb][0], s[0][jb][1]),
                             fmaxf(s[0][jb][2], s[0][jb][3]));
            float m1 = fmaxf(fmaxf(s[1][jb][0], s[1][jb][1]),
                             fmaxf(s[1][jb][2], s[1][jb][3]));
            float mm = fmaxf(m0, m1);
            mm = fmaxf(mm, __shfl_xor(mm, 16));
            mm = fmaxf(mm, __shfl_xor(mm, 32));
            pmax[jb] = mm;
        }
        if (h == 0) { wmax[w][0][j16] = pmax[0]; wmax[w][1][j16] = pmax[1]; }
        __syncthreads();

        float m_new[2], sc[2];
#pragma unroll
        for (int jb = 0; jb < 2; ++jb) {
            float tm = wmax[0][jb][j16];
#pragma unroll
            for (int w2 = 1; w2 < 8; ++w2) tm = fmaxf(tm, wmax[w2][jb][j16]);
            m_new[jb] = fmaxf(m_run[jb], tm);
            sc[jb]    = __expf(m_run[jb] - m_new[jb]);
            m_run[jb] = m_new[jb];
        }

        float psum[2] = {0.f, 0.f};
#pragma unroll
        for (int ib = 0; ib < 2; ++ib) {
#pragma unroll
            for (int jb = 0; jb < 2; ++jb) {
                const float p0 = __expf(s[ib][jb][0] - m_new[jb]);
                const float p1 = __expf(s[ib][jb][1] - m_new[jb]);
                const float p2 = __expf(s[ib][jb][2] - m_new[jb]);
                const float p3 = __expf(s[ib][jb][3] - m_new[jb]);
                psum[jb] += (p0 + p1) + (p2 + p3);
                f16x4 v4;
                v4[0] = (f16)p0; v4[1] = (f16)p1; v4[2] = (f16)p2; v4[3] = (f16)p3;
                const int jloc = 16 * jb + j16;
                const int sw   = (4 * w + 2 * ib + (h >> 1)) ^ j16;
                *(f16x4*)&Pp[jloc * 256 + sw * 8 + (h & 1) * 4] = v4;
            }
        }
#pragma unroll
        for (int jb = 0; jb < 2; ++jb) {
            psum[jb] += __shfl_xor(psum[jb], 16);
            psum[jb] += __shfl_xor(psum[jb], 32);
        }
        if (h == 0) { wsum[w][0][j16] = psum[0]; wsum[w][1][j16] = psum[1]; }

#pragma unroll
        for (int cb = 0; cb < 4; ++cb)
#pragma unroll
            for (int jb = 0; jb < 2; ++jb)
#pragma unroll
                for (int r = 0; r < 4; ++r) oacc[cb][jb][r] *= sc[jb];

        __syncthreads();

#pragma unroll
        for (int jb = 0; jb < 2; ++jb) {
            float ts = 0.f;
#pragma unroll
            for (int w2 = 0; w2 < 8; ++w2) ts += wsum[w2][jb][j16];
            l_run[jb] = l_run[jb] * sc[jb] + ts;
        }

        const int i0n = (it < 15) ? (i0 + 256) : 0;
        {
            const int irow0 = i0n + 32 * w + j16;
            fa[0][0] = *(const f16x8*)(fbase + (size_t)irow0 * CQ + 8 * h);
            fa[0][1] = *(const f16x8*)(fbase + (size_t)irow0 * CQ + 32 + 8 * h);
            fa[1][0] = *(const f16x8*)(fbase + (size_t)(irow0 + 16) * CQ + 8 * h);
            fa[1][1] = *(const f16x8*)(fbase + (size_t)(irow0 + 16) * CQ + 32 + 8 * h);
        }
        PVSTF(aA, 0); LDAF(aA, 2, i0);
        PVSTF(aB, 1); LDAF(aB, 3, i0);
        PVSTF(aA, 2); LDAF(aA, 4, i0);
        PVSTF(aB, 3); LDAF(aB, 5, i0);
        PVSTF(aA, 4); LDAF(aA, 6, i0);
        PVSTF(aB, 5); LDAF(aB, 7, i0);
        PVSTF(aA, 6); LDAF(aA, 0, i0n);
        PVSTF(aB, 7); LDAF(aB, 1, i0n);
    }

    float gam;
    if (isbf) gam = bf2f(((const u16*)gammap)[0]);
    else      gam = ((const float*)gammap)[0];

    const float inv0 = gam / l_run[0];
    const float inv1 = gam / l_run[1];

#pragma unroll
    for (int cb = 0; cb < 4; ++cb) {
#pragma unroll
        for (int jb = 0; jb < 2; ++jb) {
            const float invj = jb ? inv1 : inv0;
            const int j = j0 + 16 * jb + j16;
#pragma unroll
            for (int r = 0; r < 4; ++r) {
                const int c = 64 * w + 16 * cb + 4 * h + r;
                const size_t idx = ((size_t)b * CH + c) * NN + j;
                float xv;
                if (isbf) xv = bf2f(((const u16*)xin)[idx]);
                else      xv = ((const float*)xin)[idx];
                out[idx] = oacc[cb][jb][r] * invj + xv;
            }
        }
    }
#undef LDAF
#undef PVSTF
}

extern "C" void kernel_launch(void* const* d_in, const int* in_sizes, int n_in,
                              void* d_out, int out_size, void* d_ws, size_t ws_size,
                              hipStream_t stream)
{
    const size_t off_l  = 256;
    const size_t off_m  = off_l  + (size_t)BATCH * NN * 4;          // lsum 64KB
    const size_t off_fT = off_m  + (size_t)BATCH * NN * 64 * 4;     // mb 4MB
    const size_t off_gT = off_fT + (size_t)BATCH * NN * CQ * 2;
    const size_t off_hv = off_gT + (size_t)BATCH * NN * CQ * 2;
    const size_t off_xT = off_hv + (size_t)BATCH * CH * NN * 2;
    const size_t off_Wc = off_xT + (size_t)BATCH * NN * CH * 2;     // xT 16MB
    const size_t off_ST = off_Wc + (size_t)640 * CH * 2;            // Wc 0.66MB
    const size_t stN    = (size_t)NN * NN * 2;

    int*   flag = (int*)d_ws;
    float* lsum = (float*)((char*)d_ws + off_l);
    float* mb   = (float*)((char*)d_ws + off_m);
    f16*   fT   = (f16*)((char*)d_ws + off_fT);
    f16*   gT   = (f16*)((char*)d_ws + off_gT);
    f16*   hv   = (f16*)((char*)d_ws + off_hv);
    f16*   xT   = (f16*)((char*)d_ws + off_xT);
    f16*   Wc   = (f16*)((char*)d_ws + off_Wc);
    f16*   ST   = (f16*)((char*)d_ws + off_ST);

    int bc = 0;
    if      (ws_size >= off_ST + 4 * stN) bc = 4;
    else if (ws_size >= off_ST + 2 * stN) bc = 2;
    else if (ws_size >= off_ST + 1 * stN) bc = 1;

    detect_kernel<<<1, 64, 0, stream>>>((const u32*)d_in[0], flag);
    wconv_kernel<<<640, 256, 0, stream>>>(d_in[1], d_in[2], d_in[3], flag, Wc);
    xpose_kernel<<<dim3(64, 8, BATCH), 256, 0, stream>>>(d_in[0], flag, xT);
    proj_mfma<<<dim3(5, 32, BATCH), 512, 0, stream>>>(Wc, xT, fT, gT, hv);

    if (bc) {
        hipMemsetAsync(lsum, 0, (size_t)BATCH * NN * 4, stream);
        for (int b0 = 0; b0 < BATCH; b0 += bc) {
            dim3 g1(32, 32, bc);
            score_kernel<<<g1, 512, 0, stream>>>(fT, gT, ST, lsum, mb, b0);
            pv_kernel<<<128 * bc, 512, 0, stream>>>(d_in[0], hv, ST, lsum, mb,
                                                    d_in[4], flag,
                                                    (float*)d_out, b0, bc);
        }
    } else {
        attn_mfma<<<512, 512, 0, stream>>>(d_in[0], fT, gT, hv, d_in[4],
                                           flag, (float*)d_out);
    }
}